// Round 22
// baseline (2432.496 us; speedup 1.0000x reference)
//
#include <hip/hip_runtime.h>
#include <math.h>

#define BB 64      // batch
#define SS 512     // seq len
#define HH 256     // hidden
#define NC 9       // classes
#define G4 1024    // 4*H gates (one direction)
#define TCLOG 7
#define TC 128     // time chunk
#define NCH (SS / TC)

#define KLQ 9      // int8 k16 chunks cached in LDS = 144 KB; 7 streamed int8

typedef _Float16 half2v __attribute__((ext_vector_type(2)));
typedef uint  v4u __attribute__((ext_vector_type(4)));
typedef float v4f __attribute__((ext_vector_type(4)));

// ---------- non-temporal vector loads (keep dwordx4, demote L2 residency) ----------
__device__ __forceinline__ uint4 ntld_u4(const void* p) {
    v4u v = __builtin_nontemporal_load((const v4u*)p);
    uint4 r; r.x = v.x; r.y = v.y; r.z = v.z; r.w = v.w; return r;
}
__device__ __forceinline__ float4 ntld_f4(const void* p) {
    v4f v = __builtin_nontemporal_load((const v4f*)p);
    float4 r; r.x = v.x; r.y = v.y; r.z = v.z; r.w = v.w; return r;
}

// ---------- activations ----------
__device__ __forceinline__ float sigf(float x) {
    return 1.0f / (1.0f + __expf(-x));
}
__device__ __forceinline__ float tanhfast(float x) {
    float a = fabsf(x);
    float e = __expf(-2.0f * a);
    float t = (1.0f - e) / (1.0f + e);
    return copysignf(t, x);
}
__device__ __forceinline__ float dot8h(uint4 w, uint4 h, float acc) {
    acc = __builtin_amdgcn_fdot2(__builtin_bit_cast(half2v, w.x),
                                 __builtin_bit_cast(half2v, h.x), acc, false);
    acc = __builtin_amdgcn_fdot2(__builtin_bit_cast(half2v, w.y),
                                 __builtin_bit_cast(half2v, h.y), acc, false);
    acc = __builtin_amdgcn_fdot2(__builtin_bit_cast(half2v, w.z),
                                 __builtin_bit_cast(half2v, h.z), acc, false);
    acc = __builtin_amdgcn_fdot2(__builtin_bit_cast(half2v, w.w),
                                 __builtin_bit_cast(half2v, h.w), acc, false);
    return acc;
}
__device__ __forceinline__ int dot16q(uint4 w, uint4 h, int acc) {
    acc = __builtin_amdgcn_sdot4((int)w.x, (int)h.x, acc, false);
    acc = __builtin_amdgcn_sdot4((int)w.y, (int)h.y, acc, false);
    acc = __builtin_amdgcn_sdot4((int)w.z, (int)h.z, acc, false);
    acc = __builtin_amdgcn_sdot4((int)w.w, (int)h.w, acc, false);
    return acc;
}
__device__ __forceinline__ ushort f16b(float x) {
    return __builtin_bit_cast(ushort, (_Float16)x);
}

// ---------- job descriptors ----------
struct GJob {
    const void*  A;
    const int*   tok;
    const void*  W;
    const float* sw;
    const float* bias;
    ushort*      out;
    int tb, ts, is8, pad;
};
struct SJob {
    const ushort* xgF; const ushort* xgB;
    const uint*  wTq; const float* swf; const float* bhh2;
    ushort* hout; unsigned char* hout8; float* state;
    int doW8, tbF, tbB, doInit;
};
struct MegaP {
    SJob s;
    GJob g[4];
    int nScan, nGemm;
};

__device__ __forceinline__ int pad4(int r) { return r + (r >> 3); }

// f16 GEMM (layer 0, K=128, emb gather), NT global reads
__device__ void gemm16_dev(unsigned char* sm, const GJob& G, int bx, int by) {
    uint4* As = (uint4*)sm;          // [2][144]
    uint4* Bs = As + 288;
    const int tid = threadIdx.x;
    const int m0 = bx * 128, n0 = by * 128;
    const int lr = tid & 127, lk8 = (tid >> 7) & 1;
    const int lpad = lr + (lr >> 3);
    const bool isA = tid < 256, isB = (tid >= 256 && tid < 512);
    const int tcc = (m0 + lr) & (TC - 1);
    const int bb  = (m0 + lr) >> TCLOG;
    const int tglob = G.tb + G.ts * tcc;
    const long arow = (long)bb * SS + tglob;
    const float*  Af = isA ? ((const float*)G.A + (long)G.tok[arow] * 128 + lk8 * 8) : nullptr;
    const ushort* Wp = isB ? ((const ushort*)G.W + (long)(n0 + lr) * 128 + lk8 * 8) : nullptr;
    const int tr = tid >> 5, tn = tid & 31;

    float acc[4][4];
    #pragma unroll
    for (int i = 0; i < 4; i++)
        #pragma unroll
        for (int j = 0; j < 4; j++) acc[i][j] = 0.f;

    #pragma unroll 1
    for (int k0 = 0; k0 < 128; k0 += 16) {
        if (isA) {
            float4 a0 = ntld_f4(Af + k0);
            float4 a1 = ntld_f4(Af + k0 + 4);
            uint4 aw;
            aw.x = (uint)f16b(a0.x) | ((uint)f16b(a0.y) << 16);
            aw.y = (uint)f16b(a0.z) | ((uint)f16b(a0.w) << 16);
            aw.z = (uint)f16b(a1.x) | ((uint)f16b(a1.y) << 16);
            aw.w = (uint)f16b(a1.z) | ((uint)f16b(a1.w) << 16);
            As[lk8 * 144 + lpad] = aw;
        } else if (isB) {
            Bs[lk8 * 144 + lpad] = ntld_u4(Wp + k0);
        }
        __syncthreads();
        #pragma unroll
        for (int k8 = 0; k8 < 2; k8++) {
            uint4 a[4], w[4];
            #pragma unroll
            for (int i = 0; i < 4; i++) {
                a[i] = As[k8 * 144 + pad4(tr * 4 + i)];
                w[i] = Bs[k8 * 144 + pad4(tn * 4 + i)];
            }
            #pragma unroll
            for (int i = 0; i < 4; i++)
                #pragma unroll
                for (int j = 0; j < 4; j++)
                    acc[i][j] = dot8h(w[j], a[i], acc[i][j]);
        }
        __syncthreads();
    }

    float4 bc = *(const float4*)(G.bias + n0 + tn * 4);
    #pragma unroll
    for (int i = 0; i < 4; i++) {
        ushort4 o;
        o.x = f16b(acc[i][0] + bc.x);
        o.y = f16b(acc[i][1] + bc.y);
        o.z = f16b(acc[i][2] + bc.z);
        o.w = f16b(acc[i][3] + bc.w);
        *(ushort4*)(G.out + (long)(m0 + tr * 4 + i) * G4 + n0 + tn * 4) = o;
    }
}

// int8 GEMM (layer 1, K=512, A = H08), NT global reads
__device__ void gemm8_dev(unsigned char* sm, const GJob& G, int bx, int by) {
    uint4* As = (uint4*)sm;          // [144]
    uint4* Bs = As + 144;
    const int tid = threadIdx.x;
    const int m0 = bx * 128, n0 = by * 128;
    const int lr = tid & 127;
    const int lpad = lr + (lr >> 3);
    const bool isA = tid < 128, isB = (tid >= 128 && tid < 256);
    const int tcc = (m0 + lr) & (TC - 1);
    const int bb  = (m0 + lr) >> TCLOG;
    const int tglob = G.tb + G.ts * tcc;
    const long arow = (long)bb * SS + tglob;
    const uint4* Ap = isA ? (const uint4*)((const unsigned char*)G.A + arow * 512) : nullptr;
    const uint4* Wp = isB ? ((const uint4*)G.W + (long)(n0 + lr) * 32) : nullptr;
    const int tr = tid >> 5, tn = tid & 31;

    int acc[4][4];
    #pragma unroll
    for (int i = 0; i < 4; i++)
        #pragma unroll
        for (int j = 0; j < 4; j++) acc[i][j] = 0;

    #pragma unroll 1
    for (int k0 = 0; k0 < 32; k0++) {
        if (isA) As[lpad] = ntld_u4(Ap + k0);
        else if (isB) Bs[lpad] = ntld_u4(Wp + k0);
        __syncthreads();
        uint4 a[4], w[4];
        #pragma unroll
        for (int i = 0; i < 4; i++) {
            a[i] = As[pad4(tr * 4 + i)];
            w[i] = Bs[pad4(tn * 4 + i)];
        }
        #pragma unroll
        for (int i = 0; i < 4; i++)
            #pragma unroll
            for (int j = 0; j < 4; j++)
                acc[i][j] = dot16q(w[j], a[i], acc[i][j]);
        __syncthreads();
    }

    #pragma unroll
    for (int i = 0; i < 4; i++) {
        ushort4 o;
        #pragma unroll
        for (int j = 0; j < 4; j++) {
            float r = fmaf((float)acc[i][j], G.sw[n0 + tn * 4 + j], G.bias[n0 + tn * 4 + j]);
            ((ushort*)&o)[j] = f16b(r);
        }
        *(ushort4*)(G.out + (long)(m0 + tr * 4 + i) * G4 + n0 + tn * 4) = o;
    }
}

// int8-dot LSTM scan (proven body; xg is f16)
__device__ void scan_dev(unsigned char* sm, const SJob& S, int b, int d) {
    const int j = threadIdx.x;
    const ushort* xg = (d ? S.xgB : S.xgF) + (long)b * TC * G4 + j;
    const uint4* wTd = (const uint4*)S.wTq + (long)d * 16 * 1024;

    uint4* lwq = (uint4*)sm;                      // 147456 B
    float* gl  = (float*)(sm + 147456);           // 4096 B
    uint*  hq  = (uint*)(sm + 147456 + 4096);     // 512 B

    #pragma unroll
    for (int kc = 0; kc < KLQ; kc++)
        lwq[kc * 1024 + j] = wTd[(long)kc * 1024 + j];

    const float bj  = S.bhh2[d * G4 + j];
    const float scl = S.swf[d * G4 + j];
    float c_reg = 0.f, h_reg = 0.f;
    if (j < HH) {
        if (!S.doInit) {
            h_reg = S.state[((d * BB + b) * 2 + 0) * HH + j];
            c_reg = S.state[((d * BB + b) * 2 + 1) * HH + j];
        }
        ((char*)hq)[j] = (char)__float2int_rn(h_reg * 127.f);
    }
    __syncthreads();

    #pragma unroll 1
    for (int tc = 0; tc < TC; ++tc) {
        const int rb = tc & 1;
        const uint4* hc = (const uint4*)(hq + rb * 64);
        int isum = 0;
        #pragma unroll
        for (int kc = 0; kc < KLQ; kc++)
            isum = dot16q(lwq[kc * 1024 + j], hc[kc], isum);
        #pragma unroll
        for (int kc = KLQ; kc < 16; kc++)
            isum = dot16q(wTd[(long)kc * 1024 + j], hc[kc], isum);

        float xv = (float)__builtin_bit_cast(_Float16, xg[(long)tc * G4]);
        gl[j] = fmaf((float)isum, scl, xv + bj);
        __syncthreads();
        if (j < HH) {
            float gi = gl[j], gf = gl[j + 256], gg = gl[j + 512], go = gl[j + 768];
            c_reg = sigf(gf) * c_reg + sigf(gi) * tanhfast(gg);
            float h = sigf(go) * tanhfast(c_reg);
            h_reg = h;
            int qh = __float2int_rn(h * 127.f);
            ((char*)(hq + (rb ^ 1) * 64))[j] = (char)qh;
            const int t = d ? (S.tbB - tc) : (S.tbF + tc);
            if (S.doW8) S.hout8[((long)(b * SS + t)) * 512 + d * HH + j] = (unsigned char)(char)qh;
            else        S.hout [((long)(b * SS + t)) * 512 + d * HH + j] = f16b(h);
        }
        __syncthreads();
    }

    if (j < HH) {
        S.state[((d * BB + b) * 2 + 0) * HH + j] = h_reg;
        S.state[((d * BB + b) * 2 + 1) * HH + j] = c_reg;
    }
}

// ---------- mega kernel: scan blocks first, then gemm tiles ----------
__global__ __launch_bounds__(1024, 4) void mega(MegaP p) {
    __shared__ __align__(16) unsigned char sm[152064];
    const int blk = blockIdx.x;
    if (blk < p.nScan * 128) {
        const int local = blk & 127;
        scan_dev(sm, p.s, local & 63, local >> 6);
    } else {
        const int gb = blk - p.nScan * 128;
        const int job = gb >> 9, t = gb & 511;
        const GJob& G = p.g[job];
        if (G.is8) gemm8_dev(sm, G, t & 63, t >> 6);
        else       gemm16_dev(sm, G, t & 63, t >> 6);
    }
}

// ---------- preprocessing (proven) ----------
__global__ void quant_whh(const float* __restrict__ whh, uint* __restrict__ wTq,
                          float* __restrict__ swf) {
    const int row = blockIdx.x;
    const int t = threadIdx.x;
    float4 v = *(const float4*)(whh + (long)row * 256 + t * 4);
    float mx = fmaxf(fmaxf(fabsf(v.x), fabsf(v.y)), fmaxf(fabsf(v.z), fabsf(v.w)));
    #pragma unroll
    for (int o = 32; o > 0; o >>= 1) mx = fmaxf(mx, __shfl_xor(mx, o));
    float inv = (mx > 0.f) ? 127.f / mx : 0.f;
    int q0 = (int)rintf(v.x * inv) & 255;
    int q1 = (int)rintf(v.y * inv) & 255;
    int q2 = (int)rintf(v.z * inv) & 255;
    int q3 = (int)rintf(v.w * inv) & 255;
    uint u = (uint)q0 | ((uint)q1 << 8) | ((uint)q2 << 16) | ((uint)q3 << 24);
    const int dir = row >> 10, j = row & 1023;
    const int kc = t >> 2, l4 = t & 3;
    wTq[(((long)(dir * 16 + kc) * 1024 + j) << 2) + l4] = u;
    if (t == 0) swf[row] = (mx > 0.f) ? (mx / 127.f) * (1.f / 127.f) : 0.f;
}

__global__ void quant_wih1(const float* __restrict__ w, uint* __restrict__ wq,
                           float* __restrict__ swf) {
    const int row = blockIdx.x;
    const int t = threadIdx.x;
    float4 a = *(const float4*)(w + (long)row * 512 + t * 8);
    float4 b = *(const float4*)(w + (long)row * 512 + t * 8 + 4);
    float mx = fmaxf(fmaxf(fmaxf(fabsf(a.x), fabsf(a.y)), fmaxf(fabsf(a.z), fabsf(a.w))),
                     fmaxf(fmaxf(fabsf(b.x), fabsf(b.y)), fmaxf(fabsf(b.z), fabsf(b.w))));
    #pragma unroll
    for (int o = 32; o > 0; o >>= 1) mx = fmaxf(mx, __shfl_xor(mx, o));
    float inv = (mx > 0.f) ? 127.f / mx : 0.f;
    uint q0 = (uint)((int)rintf(a.x * inv) & 255) | ((uint)((int)rintf(a.y * inv) & 255) << 8)
            | ((uint)((int)rintf(a.z * inv) & 255) << 16) | ((uint)((int)rintf(a.w * inv) & 255) << 24);
    uint q1 = (uint)((int)rintf(b.x * inv) & 255) | ((uint)((int)rintf(b.y * inv) & 255) << 8)
            | ((uint)((int)rintf(b.z * inv) & 255) << 16) | ((uint)((int)rintf(b.w * inv) & 255) << 24);
    wq[(long)row * 128 + t * 2]     = q0;
    wq[(long)row * 128 + t * 2 + 1] = q1;
    if (t == 0) swf[row] = (mx > 0.f) ? mx / (127.f * 127.f) : 0.f;
}

__global__ void pack_f16(const float* __restrict__ in, ushort* __restrict__ out, int n8) {
    int i = blockIdx.x * 256 + threadIdx.x;
    if (i >= n8) return;
    float4 a = *(const float4*)(in + (long)i * 8);
    float4 b = *(const float4*)(in + (long)i * 8 + 4);
    _Float16 o[8] = {(_Float16)a.x, (_Float16)a.y, (_Float16)a.z, (_Float16)a.w,
                     (_Float16)b.x, (_Float16)b.y, (_Float16)b.z, (_Float16)b.w};
    *(uint4*)(out + (long)i * 8) = *(uint4*)o;
}

// ---------- tail kernels (proven) ----------
__global__ __launch_bounds__(256) void emissions_k16(
    const ushort* __restrict__ h1, const float* __restrict__ clsw,
    const float* __restrict__ clsb, float* __restrict__ em)
{
    long u = (long)blockIdx.x * 256 + threadIdx.x;
    if (u >= (long)BB * SS * NC) return;
    int c = (int)(u % NC);
    long m = u / NC;
    const uint* hr = (const uint*)(h1 + m * 512);
    const float2* wr = (const float2*)(clsw + (long)c * 512);
    float s0 = 0, s1 = 0;
    #pragma unroll 8
    for (int q = 0; q < 256; q += 2) {
        half2v h0 = __builtin_bit_cast(half2v, hr[q]);
        half2v h1v = __builtin_bit_cast(half2v, hr[q + 1]);
        float2 w0 = wr[q], w1 = wr[q + 1];
        s0 += (float)h0.x * w0.x + (float)h0.y * w0.y;
        s1 += (float)h1v.x * w1.x + (float)h1v.y * w1.y;
    }
    em[u] = s0 + s1 + clsb[c];
}

__global__ __launch_bounds__(64) void crf_llh(
    const float* __restrict__ em, const int* __restrict__ labels,
    const int* __restrict__ mask, const float* __restrict__ start,
    const float* __restrict__ endt, const float* __restrict__ trans,
    float* __restrict__ llh)
{
    int b = blockIdx.x, j = threadIdx.x;
    bool act = j < NC;
    float tcol[NC];
    #pragma unroll
    for (int i = 0; i < NC; i++) tcol[i] = act ? trans[i * NC + j] : 0.f;
    const float* emb_ = em + (long)b * SS * NC;
    const int* lb = labels + b * SS;
    const int* mk = mask + b * SS;
    float alpha = act ? (start[j] + emb_[j]) : -1e30f;

    float num = 0.f;
    int msum = 0;
    for (int t = j; t < SS; t += 64) msum += (mk[t] != 0);
    for (int t = 1 + j; t < SS; t += 64) {
        float m = (float)mk[t];
        num += m * (trans[lb[t - 1] * NC + lb[t]] + emb_[t * NC + lb[t]]);
    }
    for (int o = 32; o > 0; o >>= 1) {
        num  += __shfl_down(num, o);
        msum += __shfl_down(msum, o);
    }
    msum = __shfl(msum, 0);

    for (int t = 1; t < SS; t++) {
        int m = mk[t];
        float emj = act ? emb_[t * NC + j] : 0.f;
        float v[NC];
        float mx = -1e30f;
        #pragma unroll
        for (int i = 0; i < NC; i++) {
            v[i] = __shfl(alpha, i) + tcol[i];
            mx = fmaxf(mx, v[i]);
        }
        float sum = 0.f;
        #pragma unroll
        for (int i = 0; i < NC; i++) sum += __expf(v[i] - mx);
        float nxt = mx + __logf(sum) + emj;
        if (m > 0 && act) alpha = nxt;
    }
    float fin = act ? alpha + endt[j] : -1e30f;
    float mx = -1e30f;
    #pragma unroll
    for (int i = 0; i < NC; i++) mx = fmaxf(mx, __shfl(fin, i));
    float s = 0.f;
    #pragma unroll
    for (int i = 0; i < NC; i++) s += __expf(__shfl(fin, i) - mx);
    float den = mx + __logf(s);
    if (j == 0) {
        int last_idx = msum - 1;
        float numer = num + start[lb[0]] + emb_[lb[0]] + endt[lb[last_idx]];
        llh[b] = numer - den;
    }
}

__global__ __launch_bounds__(64) void loss_k(const float* __restrict__ llh, float* __restrict__ out) {
    int j = threadIdx.x;
    float v = llh[j];
    for (int o = 32; o > 0; o >>= 1) v += __shfl_down(v, o);
    if (j == 0) out[0] = -v / 64.0f;
}

__global__ __launch_bounds__(64) void viterbi_k(
    const float* __restrict__ em, const int* __restrict__ mask,
    const float* __restrict__ start, const float* __restrict__ endt,
    const float* __restrict__ trans, float* __restrict__ outp)
{
    int b = blockIdx.x, j = threadIdx.x;
    bool act = j < NC;
    __shared__ unsigned char bp[SS][NC];
    float tcol[NC];
    #pragma unroll
    for (int i = 0; i < NC; i++) tcol[i] = act ? trans[i * NC + j] : 0.f;
    const float* emb_ = em + (long)b * SS * NC;
    const int* mk = mask + b * SS;
    float score = act ? (start[j] + emb_[j]) : -1e30f;

    for (int t = 1; t < SS; t++) {
        float best = 0.f;
        int bi = 0;
        #pragma unroll
        for (int i = 0; i < NC; i++) {
            float vv = __shfl(score, i) + tcol[i];
            if (i == 0 || vv > best) { best = vv; bi = i; }
        }
        int m = mk[t];
        float nxt = best + (act ? emb_[t * NC + j] : 0.f);
        if (act) {
            if (m > 0) { score = nxt; bp[t][j] = (unsigned char)bi; }
            else       { bp[t][j] = (unsigned char)j; }
        }
    }
    float fin = act ? score + endt[j] : -1e30f;
    float bestf = 0.f;
    int last = 0;
    #pragma unroll
    for (int i = 0; i < NC; i++) {
        float vv = __shfl(fin, i);
        if (i == 0 || vv > bestf) { bestf = vv; last = i; }
    }
    __syncthreads();
    if (j == 0) {
        int cur = last;
        outp[1 + (long)b * SS + (SS - 1)] = (float)cur;
        for (int t = SS - 1; t >= 1; t--) {
            cur = bp[t][cur];
            outp[1 + (long)b * SS + (t - 1)] = (float)cur;
        }
    }
}

extern "C" void kernel_launch(void* const* d_in, const int* in_sizes, int n_in,
                              void* d_out, int out_size, void* d_ws, size_t ws_size,
                              hipStream_t stream) {
    const int*   tok    = (const int*)d_in[0];
    const int*   lab    = (const int*)d_in[1];
    const int*   msk    = (const int*)d_in[2];
    const float* emb    = (const float*)d_in[3];
    const float* w_ih0  = (const float*)d_in[4];
    const float* w_hh0  = (const float*)d_in[5];
    const float* b_ih0  = (const float*)d_in[6];
    const float* b_hh0  = (const float*)d_in[7];
    const float* w_ih1  = (const float*)d_in[8];
    const float* w_hh1  = (const float*)d_in[9];
    const float* b_ih1  = (const float*)d_in[10];
    const float* b_hh1  = (const float*)d_in[11];
    const float* clsw   = (const float*)d_in[12];
    const float* clsb   = (const float*)d_in[13];
    const float* startt = (const float*)d_in[14];
    const float* endt   = (const float*)d_in[15];
    const float* transm = (const float*)d_in[16];
    float* out = (float*)d_out;

    // ---- workspace carve (f32 units); ~194 MB ----
    size_t nH8  = (size_t)BB * SS * 512 / 4;
    size_t nHh  = (size_t)BB * SS * 512 / 2;
    size_t xgHalf = (size_t)BB * TC * G4;
    size_t nXGb = xgHalf * 2 / 2;
    size_t nWQ  = (size_t)2 * 16 * 1024 * 4;
    size_t nSW  = (size_t)2 * 1024;
    size_t nWI0 = (size_t)2048 * 128 / 2;
    size_t nWQ1 = (size_t)2048 * 128;
    size_t nEM  = (size_t)BB * SS * NC;
    size_t nST  = (size_t)2 * BB * 2 * HH;

    float* H08f = (float*)d_ws;
    float* H1f  = H08f + nH8;
    float* XG0a = H1f + nHh;
    float* XG0b = XG0a + nXGb;
    float* XG1a = XG0b + nXGb;
    float* XG1b = XG1a + nXGb;
    float* WQ0  = XG1b + nXGb;
    float* WQ1w = WQ0 + nWQ;
    float* SW0  = WQ1w + nWQ;
    float* SW1  = SW0 + nSW;
    float* WI0  = SW1 + nSW;
    float* WQI1 = WI0 + nWI0;
    float* SWI1 = WQI1 + nWQ1;
    float* EM   = SWI1 + 2048;
    float* ST0  = EM + nEM;
    float* ST1  = ST0 + nST;
    float* LLH  = ST1 + nST;

    unsigned char* H08 = (unsigned char*)H08f;
    ushort* H1h  = (ushort*)H1f;
    ushort* WI0h = (ushort*)WI0;
    ushort* XG0[2] = {(ushort*)XG0a, (ushort*)XG0b};
    ushort* XG1[2] = {(ushort*)XG1a, (ushort*)XG1b};

    quant_whh<<<2048, 64, 0, stream>>>(w_hh0, (uint*)WQ0, SW0);
    quant_whh<<<2048, 64, 0, stream>>>(w_hh1, (uint*)WQ1w, SW1);
    quant_wih1<<<2048, 64, 0, stream>>>(w_ih1, (uint*)WQI1, SWI1);
    pack_f16<<<(2048 * 128 / 8 + 255) / 256, 256, 0, stream>>>(w_ih0, WI0h, 2048 * 128 / 8);

    auto g16 = [&](int c, int dd) {
        GJob g{};
        g.A = emb; g.tok = tok;
        g.W = WI0h + (size_t)dd * 1024 * 128;
        g.sw = nullptr; g.bias = b_ih0 + dd * 1024;
        g.out = XG0[c & 1] + (size_t)dd * xgHalf;
        g.tb = dd ? (SS - 1 - c * TC) : (c * TC);
        g.ts = dd ? -1 : 1;
        g.is8 = 0;
        return g;
    };
    auto g8 = [&](int c, int dd) {
        GJob g{};
        g.A = H08; g.tok = nullptr;
        g.W = (const uint*)WQI1 + (size_t)dd * 1024 * 128;
        g.sw = SWI1 + dd * 1024; g.bias = b_ih1 + dd * 1024;
        g.out = XG1[c & 1] + (size_t)dd * xgHalf;
        g.tb = dd ? (SS - 1 - c * TC) : (c * TC);
        g.ts = dd ? -1 : 1;
        g.is8 = 1;
        return g;
    };
    auto sj = [&](int layer, int c) {
        SJob s{};
        ushort* xgb = layer ? XG1[c & 1] : XG0[c & 1];
        s.xgF = xgb; s.xgB = xgb + xgHalf;
        s.wTq = (const uint*)(layer ? WQ1w : WQ0);
        s.swf = layer ? SW1 : SW0;
        s.bhh2 = layer ? b_hh1 : b_hh0;
        s.hout = H1h; s.hout8 = H08;
        s.doW8 = layer ? 0 : 1;
        s.state = layer ? ST1 : ST0;
        s.tbF = c * TC; s.tbB = SS - 1 - c * TC;
        s.doInit = (c == 0);
        return s;
    };
    auto launch = [&](int nS, SJob s, GJob* gj, int nG) {
        MegaP p{};
        p.s = s;
        for (int i = 0; i < nG; i++) p.g[i] = gj[i];
        p.nScan = nS; p.nGemm = nG;
        mega<<<nS * 128 + nG * 512, 1024, 0, stream>>>(p);
    };

    // ---- layer 0 pipeline ----
    { GJob j2[2] = {g16(0, 0), g16(0, 1)};        launch(0, SJob{}, j2, 2); }   // D1
    { GJob j2[2] = {g16(1, 0), g16(1, 1)};        launch(1, sj(0, 0), j2, 2); } // D2
    { GJob j2[2] = {g16(2, 0), g16(2, 1)};        launch(1, sj(0, 1), j2, 2); } // D3
    { GJob j2[2] = {g16(3, 0), g16(3, 1)};        launch(1, sj(0, 2), j2, 2); } // D4
    {                                              launch(1, sj(0, 3), nullptr, 0); } // D5
    // ---- layer 1 pipeline ----
    { GJob j4[4] = {g8(0, 0), g8(0, 1), g8(1, 0), g8(1, 1)}; launch(0, SJob{}, j4, 4); } // D6
    {                                              launch(1, sj(1, 0), nullptr, 0); } // D7
    { GJob j2[2] = {g8(2, 0), g8(2, 1)};          launch(1, sj(1, 1), j2, 2); } // D8
    { GJob j2[2] = {g8(3, 0), g8(3, 1)};          launch(1, sj(1, 2), j2, 2); } // D9
    {                                              launch(1, sj(1, 3), nullptr, 0); } // D10

    emissions_k16<<<((BB * SS * NC) + 255) / 256, 256, 0, stream>>>(H1h, clsw, clsb, EM);
    crf_llh<<<BB, 64, 0, stream>>>(EM, lab, msk, startt, endt, transm, LLH);
    loss_k<<<1, 64, 0, stream>>>(LLH, out);
    viterbi_k<<<BB, 64, 0, stream>>>(EM, msk, startt, endt, transm, out);
}

// Round 23
// 2083.358 us; speedup vs baseline: 1.1676x; 1.1676x over previous
//
#include <hip/hip_runtime.h>
#include <math.h>

#define BB 64      // batch
#define SS 512     // seq len
#define HH 256     // hidden
#define NC 9       // classes
#define G4 1024    // 4*H gates (one direction)
#define TCLOG 7
#define TC 128     // time chunk
#define NCH (SS / TC)

#define KLQ 9      // int8 k16 chunks cached in LDS = 144 KB; 7 streamed int8

typedef _Float16 half2v __attribute__((ext_vector_type(2)));

// ---------- activations ----------
__device__ __forceinline__ float sigf(float x) {
    return 1.0f / (1.0f + __expf(-x));
}
__device__ __forceinline__ float tanhfast(float x) {
    float a = fabsf(x);
    float e = __expf(-2.0f * a);
    float t = (1.0f - e) / (1.0f + e);
    return copysignf(t, x);
}
__device__ __forceinline__ float dot8h(uint4 w, uint4 h, float acc) {
    acc = __builtin_amdgcn_fdot2(__builtin_bit_cast(half2v, w.x),
                                 __builtin_bit_cast(half2v, h.x), acc, false);
    acc = __builtin_amdgcn_fdot2(__builtin_bit_cast(half2v, w.y),
                                 __builtin_bit_cast(half2v, h.y), acc, false);
    acc = __builtin_amdgcn_fdot2(__builtin_bit_cast(half2v, w.z),
                                 __builtin_bit_cast(half2v, h.z), acc, false);
    acc = __builtin_amdgcn_fdot2(__builtin_bit_cast(half2v, w.w),
                                 __builtin_bit_cast(half2v, h.w), acc, false);
    return acc;
}
__device__ __forceinline__ int dot16q(uint4 w, uint4 h, int acc) {
    acc = __builtin_amdgcn_sdot4((int)w.x, (int)h.x, acc, false);
    acc = __builtin_amdgcn_sdot4((int)w.y, (int)h.y, acc, false);
    acc = __builtin_amdgcn_sdot4((int)w.z, (int)h.z, acc, false);
    acc = __builtin_amdgcn_sdot4((int)w.w, (int)h.w, acc, false);
    return acc;
}
__device__ __forceinline__ ushort f16b(float x) {
    return __builtin_bit_cast(ushort, (_Float16)x);
}

// ---------- job descriptors ----------
struct GJob {
    const void*  A;
    const int*   tok;
    const void*  W;
    const float* sw;
    const float* bias;
    ushort*      out;
    int tb, ts, is8, pad;
};
struct SJob {
    const ushort* xgF; const ushort* xgB;
    const uint*  wTq; const float* swf; const float* bhh2;
    ushort* hout; unsigned char* hout8; float* state;
    int doW8, tbF, tbB, doInit;
};
struct MegaP {
    SJob s;
    GJob g[4];
    int nScan, nGemm;
};

__device__ __forceinline__ int pad4(int r) { return r + (r >> 3); }

// f16 GEMM (layer 0, K=128, emb gather)
__device__ void gemm16_dev(unsigned char* sm, const GJob& G, int bx, int by) {
    uint4* As = (uint4*)sm;          // [2][144]
    uint4* Bs = As + 288;
    const int tid = threadIdx.x;
    const int m0 = bx * 128, n0 = by * 128;
    const int lr = tid & 127, lk8 = (tid >> 7) & 1;
    const int lpad = lr + (lr >> 3);
    const bool isA = tid < 256, isB = (tid >= 256 && tid < 512);
    const int tcc = (m0 + lr) & (TC - 1);
    const int bb  = (m0 + lr) >> TCLOG;
    const int tglob = G.tb + G.ts * tcc;
    const long arow = (long)bb * SS + tglob;
    const float*  Af = isA ? ((const float*)G.A + (long)G.tok[arow] * 128 + lk8 * 8) : nullptr;
    const ushort* Wp = isB ? ((const ushort*)G.W + (long)(n0 + lr) * 128 + lk8 * 8) : nullptr;
    const int tr = tid >> 5, tn = tid & 31;

    float acc[4][4];
    #pragma unroll
    for (int i = 0; i < 4; i++)
        #pragma unroll
        for (int j = 0; j < 4; j++) acc[i][j] = 0.f;

    #pragma unroll 1
    for (int k0 = 0; k0 < 128; k0 += 16) {
        if (isA) {
            float4 a0 = *(const float4*)(Af + k0);
            float4 a1 = *(const float4*)(Af + k0 + 4);
            uint4 aw;
            aw.x = (uint)f16b(a0.x) | ((uint)f16b(a0.y) << 16);
            aw.y = (uint)f16b(a0.z) | ((uint)f16b(a0.w) << 16);
            aw.z = (uint)f16b(a1.x) | ((uint)f16b(a1.y) << 16);
            aw.w = (uint)f16b(a1.z) | ((uint)f16b(a1.w) << 16);
            As[lk8 * 144 + lpad] = aw;
        } else if (isB) {
            Bs[lk8 * 144 + lpad] = *(const uint4*)(Wp + k0);
        }
        __syncthreads();
        #pragma unroll
        for (int k8 = 0; k8 < 2; k8++) {
            uint4 a[4], w[4];
            #pragma unroll
            for (int i = 0; i < 4; i++) {
                a[i] = As[k8 * 144 + pad4(tr * 4 + i)];
                w[i] = Bs[k8 * 144 + pad4(tn * 4 + i)];
            }
            #pragma unroll
            for (int i = 0; i < 4; i++)
                #pragma unroll
                for (int j = 0; j < 4; j++)
                    acc[i][j] = dot8h(w[j], a[i], acc[i][j]);
        }
        __syncthreads();
    }

    float4 bc = *(const float4*)(G.bias + n0 + tn * 4);
    #pragma unroll
    for (int i = 0; i < 4; i++) {
        ushort4 o;
        o.x = f16b(acc[i][0] + bc.x);
        o.y = f16b(acc[i][1] + bc.y);
        o.z = f16b(acc[i][2] + bc.z);
        o.w = f16b(acc[i][3] + bc.w);
        *(ushort4*)(G.out + (long)(m0 + tr * 4 + i) * G4 + n0 + tn * 4) = o;
    }
}

// int8 GEMM (layer 1, K=512, A = H08)
__device__ void gemm8_dev(unsigned char* sm, const GJob& G, int bx, int by) {
    uint4* As = (uint4*)sm;          // [144]
    uint4* Bs = As + 144;
    const int tid = threadIdx.x;
    const int m0 = bx * 128, n0 = by * 128;
    const int lr = tid & 127;
    const int lpad = lr + (lr >> 3);
    const bool isA = tid < 128, isB = (tid >= 128 && tid < 256);
    const int tcc = (m0 + lr) & (TC - 1);
    const int bb  = (m0 + lr) >> TCLOG;
    const int tglob = G.tb + G.ts * tcc;
    const long arow = (long)bb * SS + tglob;
    const uint4* Ap = isA ? (const uint4*)((const unsigned char*)G.A + arow * 512) : nullptr;
    const uint4* Wp = isB ? ((const uint4*)G.W + (long)(n0 + lr) * 32) : nullptr;
    const int tr = tid >> 5, tn = tid & 31;

    int acc[4][4];
    #pragma unroll
    for (int i = 0; i < 4; i++)
        #pragma unroll
        for (int j = 0; j < 4; j++) acc[i][j] = 0;

    #pragma unroll 1
    for (int k0 = 0; k0 < 32; k0++) {
        if (isA) As[lpad] = Ap[k0];
        else if (isB) Bs[lpad] = Wp[k0];
        __syncthreads();
        uint4 a[4], w[4];
        #pragma unroll
        for (int i = 0; i < 4; i++) {
            a[i] = As[pad4(tr * 4 + i)];
            w[i] = Bs[pad4(tn * 4 + i)];
        }
        #pragma unroll
        for (int i = 0; i < 4; i++)
            #pragma unroll
            for (int j = 0; j < 4; j++)
                acc[i][j] = dot16q(w[j], a[i], acc[i][j]);
        __syncthreads();
    }

    #pragma unroll
    for (int i = 0; i < 4; i++) {
        ushort4 o;
        #pragma unroll
        for (int j = 0; j < 4; j++) {
            float r = fmaf((float)acc[i][j], G.sw[n0 + tn * 4 + j], G.bias[n0 + tn * 4 + j]);
            ((ushort*)&o)[j] = f16b(r);
        }
        *(ushort4*)(G.out + (long)(m0 + tr * 4 + i) * G4 + n0 + tn * 4) = o;
    }
}

// int8-dot LSTM scan (proven body; xg is f16)
__device__ void scan_dev(unsigned char* sm, const SJob& S, int b, int d) {
    const int j = threadIdx.x;
    const ushort* xg = (d ? S.xgB : S.xgF) + (long)b * TC * G4 + j;
    const uint4* wTd = (const uint4*)S.wTq + (long)d * 16 * 1024;

    uint4* lwq = (uint4*)sm;                      // 147456 B
    float* gl  = (float*)(sm + 147456);           // 4096 B
    uint*  hq  = (uint*)(sm + 147456 + 4096);     // 512 B

    #pragma unroll
    for (int kc = 0; kc < KLQ; kc++)
        lwq[kc * 1024 + j] = wTd[(long)kc * 1024 + j];

    const float bj  = S.bhh2[d * G4 + j];
    const float scl = S.swf[d * G4 + j];
    float c_reg = 0.f, h_reg = 0.f;
    if (j < HH) {
        if (!S.doInit) {
            h_reg = S.state[((d * BB + b) * 2 + 0) * HH + j];
            c_reg = S.state[((d * BB + b) * 2 + 1) * HH + j];
        }
        ((char*)hq)[j] = (char)__float2int_rn(h_reg * 127.f);
    }
    __syncthreads();

    #pragma unroll 1
    for (int tc = 0; tc < TC; ++tc) {
        const int rb = tc & 1;
        const uint4* hc = (const uint4*)(hq + rb * 64);
        int isum = 0;
        #pragma unroll
        for (int kc = 0; kc < KLQ; kc++)
            isum = dot16q(lwq[kc * 1024 + j], hc[kc], isum);
        #pragma unroll
        for (int kc = KLQ; kc < 16; kc++)
            isum = dot16q(wTd[(long)kc * 1024 + j], hc[kc], isum);

        float xv = (float)__builtin_bit_cast(_Float16, xg[(long)tc * G4]);
        gl[j] = fmaf((float)isum, scl, xv + bj);
        __syncthreads();
        if (j < HH) {
            float gi = gl[j], gf = gl[j + 256], gg = gl[j + 512], go = gl[j + 768];
            c_reg = sigf(gf) * c_reg + sigf(gi) * tanhfast(gg);
            float h = sigf(go) * tanhfast(c_reg);
            h_reg = h;
            int qh = __float2int_rn(h * 127.f);
            ((char*)(hq + (rb ^ 1) * 64))[j] = (char)qh;
            const int t = d ? (S.tbB - tc) : (S.tbF + tc);
            if (S.doW8) S.hout8[((long)(b * SS + t)) * 512 + d * HH + j] = (unsigned char)(char)qh;
            else        S.hout [((long)(b * SS + t)) * 512 + d * HH + j] = f16b(h);
        }
        __syncthreads();
    }

    if (j < HH) {
        S.state[((d * BB + b) * 2 + 0) * HH + j] = h_reg;
        S.state[((d * BB + b) * 2 + 1) * HH + j] = c_reg;
    }
}

// ---------- mega kernel: scan blocks first, then gemm tiles ----------
__global__ __launch_bounds__(1024, 4) void mega(MegaP p) {
    __shared__ __align__(16) unsigned char sm[152064];
    const int blk = blockIdx.x;
    if (blk < p.nScan * 128) {
        const int local = blk & 127;
        scan_dev(sm, p.s, local & 63, local >> 6);
    } else {
        const int gb = blk - p.nScan * 128;
        const int job = gb >> 9, t = gb & 511;
        const GJob& G = p.g[job];
        if (G.is8) gemm8_dev(sm, G, t & 63, t >> 6);
        else       gemm16_dev(sm, G, t & 63, t >> 6);
    }
}

// ---------- preprocessing (proven) ----------
__global__ void quant_whh(const float* __restrict__ whh, uint* __restrict__ wTq,
                          float* __restrict__ swf) {
    const int row = blockIdx.x;
    const int t = threadIdx.x;
    float4 v = *(const float4*)(whh + (long)row * 256 + t * 4);
    float mx = fmaxf(fmaxf(fabsf(v.x), fabsf(v.y)), fmaxf(fabsf(v.z), fabsf(v.w)));
    #pragma unroll
    for (int o = 32; o > 0; o >>= 1) mx = fmaxf(mx, __shfl_xor(mx, o));
    float inv = (mx > 0.f) ? 127.f / mx : 0.f;
    int q0 = (int)rintf(v.x * inv) & 255;
    int q1 = (int)rintf(v.y * inv) & 255;
    int q2 = (int)rintf(v.z * inv) & 255;
    int q3 = (int)rintf(v.w * inv) & 255;
    uint u = (uint)q0 | ((uint)q1 << 8) | ((uint)q2 << 16) | ((uint)q3 << 24);
    const int dir = row >> 10, j = row & 1023;
    const int kc = t >> 2, l4 = t & 3;
    wTq[(((long)(dir * 16 + kc) * 1024 + j) << 2) + l4] = u;
    if (t == 0) swf[row] = (mx > 0.f) ? (mx / 127.f) * (1.f / 127.f) : 0.f;
}

__global__ void quant_wih1(const float* __restrict__ w, uint* __restrict__ wq,
                           float* __restrict__ swf) {
    const int row = blockIdx.x;
    const int t = threadIdx.x;
    float4 a = *(const float4*)(w + (long)row * 512 + t * 8);
    float4 b = *(const float4*)(w + (long)row * 512 + t * 8 + 4);
    float mx = fmaxf(fmaxf(fmaxf(fabsf(a.x), fabsf(a.y)), fmaxf(fabsf(a.z), fabsf(a.w))),
                     fmaxf(fmaxf(fabsf(b.x), fabsf(b.y)), fmaxf(fabsf(b.z), fabsf(b.w))));
    #pragma unroll
    for (int o = 32; o > 0; o >>= 1) mx = fmaxf(mx, __shfl_xor(mx, o));
    float inv = (mx > 0.f) ? 127.f / mx : 0.f;
    uint q0 = (uint)((int)rintf(a.x * inv) & 255) | ((uint)((int)rintf(a.y * inv) & 255) << 8)
            | ((uint)((int)rintf(a.z * inv) & 255) << 16) | ((uint)((int)rintf(a.w * inv) & 255) << 24);
    uint q1 = (uint)((int)rintf(b.x * inv) & 255) | ((uint)((int)rintf(b.y * inv) & 255) << 8)
            | ((uint)((int)rintf(b.z * inv) & 255) << 16) | ((uint)((int)rintf(b.w * inv) & 255) << 24);
    wq[(long)row * 128 + t * 2]     = q0;
    wq[(long)row * 128 + t * 2 + 1] = q1;
    if (t == 0) swf[row] = (mx > 0.f) ? mx / (127.f * 127.f) : 0.f;
}

__global__ void pack_f16(const float* __restrict__ in, ushort* __restrict__ out, int n8) {
    int i = blockIdx.x * 256 + threadIdx.x;
    if (i >= n8) return;
    float4 a = *(const float4*)(in + (long)i * 8);
    float4 b = *(const float4*)(in + (long)i * 8 + 4);
    _Float16 o[8] = {(_Float16)a.x, (_Float16)a.y, (_Float16)a.z, (_Float16)a.w,
                     (_Float16)b.x, (_Float16)b.y, (_Float16)b.z, (_Float16)b.w};
    *(uint4*)(out + (long)i * 8) = *(uint4*)o;
}

// ---------- tail kernels (proven) ----------
__global__ __launch_bounds__(256) void emissions_k16(
    const ushort* __restrict__ h1, const float* __restrict__ clsw,
    const float* __restrict__ clsb, float* __restrict__ em)
{
    long u = (long)blockIdx.x * 256 + threadIdx.x;
    if (u >= (long)BB * SS * NC) return;
    int c = (int)(u % NC);
    long m = u / NC;
    const uint* hr = (const uint*)(h1 + m * 512);
    const float2* wr = (const float2*)(clsw + (long)c * 512);
    float s0 = 0, s1 = 0;
    #pragma unroll 8
    for (int q = 0; q < 256; q += 2) {
        half2v h0 = __builtin_bit_cast(half2v, hr[q]);
        half2v h1v = __builtin_bit_cast(half2v, hr[q + 1]);
        float2 w0 = wr[q], w1 = wr[q + 1];
        s0 += (float)h0.x * w0.x + (float)h0.y * w0.y;
        s1 += (float)h1v.x * w1.x + (float)h1v.y * w1.y;
    }
    em[u] = s0 + s1 + clsb[c];
}

__global__ __launch_bounds__(64) void crf_llh(
    const float* __restrict__ em, const int* __restrict__ labels,
    const int* __restrict__ mask, const float* __restrict__ start,
    const float* __restrict__ endt, const float* __restrict__ trans,
    float* __restrict__ llh)
{
    int b = blockIdx.x, j = threadIdx.x;
    bool act = j < NC;
    float tcol[NC];
    #pragma unroll
    for (int i = 0; i < NC; i++) tcol[i] = act ? trans[i * NC + j] : 0.f;
    const float* emb_ = em + (long)b * SS * NC;
    const int* lb = labels + b * SS;
    const int* mk = mask + b * SS;
    float alpha = act ? (start[j] + emb_[j]) : -1e30f;

    float num = 0.f;
    int msum = 0;
    for (int t = j; t < SS; t += 64) msum += (mk[t] != 0);
    for (int t = 1 + j; t < SS; t += 64) {
        float m = (float)mk[t];
        num += m * (trans[lb[t - 1] * NC + lb[t]] + emb_[t * NC + lb[t]]);
    }
    for (int o = 32; o > 0; o >>= 1) {
        num  += __shfl_down(num, o);
        msum += __shfl_down(msum, o);
    }
    msum = __shfl(msum, 0);

    for (int t = 1; t < SS; t++) {
        int m = mk[t];
        float emj = act ? emb_[t * NC + j] : 0.f;
        float v[NC];
        float mx = -1e30f;
        #pragma unroll
        for (int i = 0; i < NC; i++) {
            v[i] = __shfl(alpha, i) + tcol[i];
            mx = fmaxf(mx, v[i]);
        }
        float sum = 0.f;
        #pragma unroll
        for (int i = 0; i < NC; i++) sum += __expf(v[i] - mx);
        float nxt = mx + __logf(sum) + emj;
        if (m > 0 && act) alpha = nxt;
    }
    float fin = act ? alpha + endt[j] : -1e30f;
    float mx = -1e30f;
    #pragma unroll
    for (int i = 0; i < NC; i++) mx = fmaxf(mx, __shfl(fin, i));
    float s = 0.f;
    #pragma unroll
    for (int i = 0; i < NC; i++) s += __expf(__shfl(fin, i) - mx);
    float den = mx + __logf(s);
    if (j == 0) {
        int last_idx = msum - 1;
        float numer = num + start[lb[0]] + emb_[lb[0]] + endt[lb[last_idx]];
        llh[b] = numer - den;
    }
}

__global__ __launch_bounds__(64) void loss_k(const float* __restrict__ llh, float* __restrict__ out) {
    int j = threadIdx.x;
    float v = llh[j];
    for (int o = 32; o > 0; o >>= 1) v += __shfl_down(v, o);
    if (j == 0) out[0] = -v / 64.0f;
}

__global__ __launch_bounds__(64) void viterbi_k(
    const float* __restrict__ em, const int* __restrict__ mask,
    const float* __restrict__ start, const float* __restrict__ endt,
    const float* __restrict__ trans, float* __restrict__ outp)
{
    int b = blockIdx.x, j = threadIdx.x;
    bool act = j < NC;
    __shared__ unsigned char bp[SS][NC];
    float tcol[NC];
    #pragma unroll
    for (int i = 0; i < NC; i++) tcol[i] = act ? trans[i * NC + j] : 0.f;
    const float* emb_ = em + (long)b * SS * NC;
    const int* mk = mask + b * SS;
    float score = act ? (start[j] + emb_[j]) : -1e30f;

    for (int t = 1; t < SS; t++) {
        float best = 0.f;
        int bi = 0;
        #pragma unroll
        for (int i = 0; i < NC; i++) {
            float vv = __shfl(score, i) + tcol[i];
            if (i == 0 || vv > best) { best = vv; bi = i; }
        }
        int m = mk[t];
        float nxt = best + (act ? emb_[t * NC + j] : 0.f);
        if (act) {
            if (m > 0) { score = nxt; bp[t][j] = (unsigned char)bi; }
            else       { bp[t][j] = (unsigned char)j; }
        }
    }
    float fin = act ? score + endt[j] : -1e30f;
    float bestf = 0.f;
    int last = 0;
    #pragma unroll
    for (int i = 0; i < NC; i++) {
        float vv = __shfl(fin, i);
        if (i == 0 || vv > bestf) { bestf = vv; last = i; }
    }
    __syncthreads();
    if (j == 0) {
        int cur = last;
        outp[1 + (long)b * SS + (SS - 1)] = (float)cur;
        for (int t = SS - 1; t >= 1; t--) {
            cur = bp[t][cur];
            outp[1 + (long)b * SS + (t - 1)] = (float)cur;
        }
    }
}

extern "C" void kernel_launch(void* const* d_in, const int* in_sizes, int n_in,
                              void* d_out, int out_size, void* d_ws, size_t ws_size,
                              hipStream_t stream) {
    const int*   tok    = (const int*)d_in[0];
    const int*   lab    = (const int*)d_in[1];
    const int*   msk    = (const int*)d_in[2];
    const float* emb    = (const float*)d_in[3];
    const float* w_ih0  = (const float*)d_in[4];
    const float* w_hh0  = (const float*)d_in[5];
    const float* b_ih0  = (const float*)d_in[6];
    const float* b_hh0  = (const float*)d_in[7];
    const float* w_ih1  = (const float*)d_in[8];
    const float* w_hh1  = (const float*)d_in[9];
    const float* b_ih1  = (const float*)d_in[10];
    const float* b_hh1  = (const float*)d_in[11];
    const float* clsw   = (const float*)d_in[12];
    const float* clsb   = (const float*)d_in[13];
    const float* startt = (const float*)d_in[14];
    const float* endt   = (const float*)d_in[15];
    const float* transm = (const float*)d_in[16];
    float* out = (float*)d_out;

    // ---- workspace carve (f32 units); ~194 MB ----
    size_t nH8  = (size_t)BB * SS * 512 / 4;
    size_t nHh  = (size_t)BB * SS * 512 / 2;
    size_t xgHalf = (size_t)BB * TC * G4;
    size_t nXGb = xgHalf * 2 / 2;
    size_t nWQ  = (size_t)2 * 16 * 1024 * 4;
    size_t nSW  = (size_t)2 * 1024;
    size_t nWI0 = (size_t)2048 * 128 / 2;
    size_t nWQ1 = (size_t)2048 * 128;
    size_t nEM  = (size_t)BB * SS * NC;
    size_t nST  = (size_t)2 * BB * 2 * HH;

    float* H08f = (float*)d_ws;
    float* H1f  = H08f + nH8;
    float* XG0a = H1f + nHh;
    float* XG0b = XG0a + nXGb;
    float* XG1a = XG0b + nXGb;
    float* XG1b = XG1a + nXGb;
    float* WQ0  = XG1b + nXGb;
    float* WQ1w = WQ0 + nWQ;
    float* SW0  = WQ1w + nWQ;
    float* SW1  = SW0 + nSW;
    float* WI0  = SW1 + nSW;
    float* WQI1 = WI0 + nWI0;
    float* SWI1 = WQI1 + nWQ1;
    float* EM   = SWI1 + 2048;
    float* ST0  = EM + nEM;
    float* ST1  = ST0 + nST;
    float* LLH  = ST1 + nST;

    unsigned char* H08 = (unsigned char*)H08f;
    ushort* H1h  = (ushort*)H1f;
    ushort* WI0h = (ushort*)WI0;
    ushort* XG0[2] = {(ushort*)XG0a, (ushort*)XG0b};
    ushort* XG1[2] = {(ushort*)XG1a, (ushort*)XG1b};

    quant_whh<<<2048, 64, 0, stream>>>(w_hh0, (uint*)WQ0, SW0);
    quant_whh<<<2048, 64, 0, stream>>>(w_hh1, (uint*)WQ1w, SW1);
    quant_wih1<<<2048, 64, 0, stream>>>(w_ih1, (uint*)WQI1, SWI1);
    pack_f16<<<(2048 * 128 / 8 + 255) / 256, 256, 0, stream>>>(w_ih0, WI0h, 2048 * 128 / 8);

    auto g16 = [&](int c, int dd) {
        GJob g{};
        g.A = emb; g.tok = tok;
        g.W = WI0h + (size_t)dd * 1024 * 128;
        g.sw = nullptr; g.bias = b_ih0 + dd * 1024;
        g.out = XG0[c & 1] + (size_t)dd * xgHalf;
        g.tb = dd ? (SS - 1 - c * TC) : (c * TC);
        g.ts = dd ? -1 : 1;
        g.is8 = 0;
        return g;
    };
    auto g8 = [&](int c, int dd) {
        GJob g{};
        g.A = H08; g.tok = nullptr;
        g.W = (const uint*)WQI1 + (size_t)dd * 1024 * 128;
        g.sw = SWI1 + dd * 1024; g.bias = b_ih1 + dd * 1024;
        g.out = XG1[c & 1] + (size_t)dd * xgHalf;
        g.tb = dd ? (SS - 1 - c * TC) : (c * TC);
        g.ts = dd ? -1 : 1;
        g.is8 = 1;
        return g;
    };
    auto sj = [&](int layer, int c) {
        SJob s{};
        ushort* xgb = layer ? XG1[c & 1] : XG0[c & 1];
        s.xgF = xgb; s.xgB = xgb + xgHalf;
        s.wTq = (const uint*)(layer ? WQ1w : WQ0);
        s.swf = layer ? SW1 : SW0;
        s.bhh2 = layer ? b_hh1 : b_hh0;
        s.hout = H1h; s.hout8 = H08;
        s.doW8 = layer ? 0 : 1;
        s.state = layer ? ST1 : ST0;
        s.tbF = c * TC; s.tbB = SS - 1 - c * TC;
        s.doInit = (c == 0);
        return s;
    };
    auto launch = [&](int nS, SJob s, GJob* gj, int nG) {
        MegaP p{};
        p.s = s;
        for (int i = 0; i < nG; i++) p.g[i] = gj[i];
        p.nScan = nS; p.nGemm = nG;
        mega<<<nS * 128 + nG * 512, 1024, 0, stream>>>(p);
    };

    // ---- pipeline: 9 megas (D6 eliminated; bridge gemms ride D4/D5) ----
    // Dependencies: g8(0) needs scan(0,0) [D2]; g8(1) needs scan(0,1) [D3];
    // g8(2) needs scan(0,2) [D4]; g8(3) needs scan(0,3) [D5].
    // Ring-2 parity: writer of XG[p] is >=1 dispatch after the reader of XG[p].
    { GJob j2[2] = {g16(0, 0), g16(0, 1)};        launch(0, SJob{}, j2, 2); }   // D1
    { GJob j2[2] = {g16(1, 0), g16(1, 1)};        launch(1, sj(0, 0), j2, 2); } // D2
    { GJob j2[2] = {g16(2, 0), g16(2, 1)};        launch(1, sj(0, 1), j2, 2); } // D3
    { GJob j4[4] = {g16(3, 0), g16(3, 1), g8(0, 0), g8(0, 1)};
                                                   launch(1, sj(0, 2), j4, 4); } // D4
    { GJob j2[2] = {g8(1, 0), g8(1, 1)};          launch(1, sj(0, 3), j2, 2); } // D5
    {                                              launch(1, sj(1, 0), nullptr, 0); } // D7
    { GJob j2[2] = {g8(2, 0), g8(2, 1)};          launch(1, sj(1, 1), j2, 2); } // D8
    { GJob j2[2] = {g8(3, 0), g8(3, 1)};          launch(1, sj(1, 2), j2, 2); } // D9
    {                                              launch(1, sj(1, 3), nullptr, 0); } // D10

    emissions_k16<<<((BB * SS * NC) + 255) / 256, 256, 0, stream>>>(H1h, clsw, clsb, EM);
    crf_llh<<<BB, 64, 0, stream>>>(EM, lab, msk, startt, endt, transm, LLH);
    loss_k<<<1, 64, 0, stream>>>(LLH, out);
    viterbi_k<<<BB, 64, 0, stream>>>(EM, msk, startt, endt, transm, out);
}

// Round 24
// 2042.069 us; speedup vs baseline: 1.1912x; 1.0202x over previous
//
#include <hip/hip_runtime.h>
#include <math.h>

#define BB 64      // batch
#define SS 512     // seq len
#define HH 256     // hidden
#define NC 9       // classes
#define G4 1024    // 4*H gates (one direction)
#define TCLOG 7
#define TC 128     // time chunk
#define NCH (SS / TC)
#define VV 30000   // vocab

#define KLQ 9      // int8 k16 chunks cached in LDS = 144 KB; 7 streamed int8

typedef _Float16 half2v __attribute__((ext_vector_type(2)));

// ---------- activations ----------
__device__ __forceinline__ float sigf(float x) {
    return 1.0f / (1.0f + __expf(-x));
}
__device__ __forceinline__ float tanhfast(float x) {
    float a = fabsf(x);
    float e = __expf(-2.0f * a);
    float t = (1.0f - e) / (1.0f + e);
    return copysignf(t, x);
}
__device__ __forceinline__ int dot16q(uint4 w, uint4 h, int acc) {
    acc = __builtin_amdgcn_sdot4((int)w.x, (int)h.x, acc, false);
    acc = __builtin_amdgcn_sdot4((int)w.y, (int)h.y, acc, false);
    acc = __builtin_amdgcn_sdot4((int)w.z, (int)h.z, acc, false);
    acc = __builtin_amdgcn_sdot4((int)w.w, (int)h.w, acc, false);
    return acc;
}
__device__ __forceinline__ ushort f16b(float x) {
    return __builtin_bit_cast(ushort, (_Float16)x);
}

// ---------- job descriptors ----------
struct GJob {
    const unsigned char* A;   // int8 rows (emb8 or H08)
    const int*   tok;         // L0 gather only
    const unsigned char* W;   // int8 rows
    const float* sw;          // per-n-row scale
    const float* swA;         // per-token scale (L0 only)
    const float* bias;
    ushort*      out;
    int tb, ts, is8, pad;     // is8: 1 = K512 (h*127 A), 2 = K128 (emb, dual scale)
};
struct SJob {
    const ushort* xgF; const ushort* xgB;
    const uint*  wTq; const float* swf; const float* bhh2;
    ushort* hout; unsigned char* hout8; float* state;
    int doW8, tbF, tbB, doInit;
};
struct MegaP {
    SJob s;
    GJob g[4];
    int nScan, nGemm;
};

__device__ __forceinline__ int pad4(int r) { return r + (r >> 3); }

// int8 GEMM, K=512 (layer 1, A = H08 = h*127, single scale)
__device__ void gemm8_dev(unsigned char* sm, const GJob& G, int bx, int by) {
    uint4* As = (uint4*)sm;          // [144]
    uint4* Bs = As + 144;
    const int tid = threadIdx.x;
    const int m0 = bx * 128, n0 = by * 128;
    const int lr = tid & 127;
    const int lpad = lr + (lr >> 3);
    const bool isA = tid < 128, isB = (tid >= 128 && tid < 256);
    const int tcc = (m0 + lr) & (TC - 1);
    const int bb  = (m0 + lr) >> TCLOG;
    const int tglob = G.tb + G.ts * tcc;
    const long arow = (long)bb * SS + tglob;
    const uint4* Ap = isA ? (const uint4*)(G.A + arow * 512) : nullptr;
    const uint4* Wp = isB ? (const uint4*)(G.W + (long)(n0 + lr) * 512) : nullptr;
    const int tr = tid >> 5, tn = tid & 31;

    int acc[4][4];
    #pragma unroll
    for (int i = 0; i < 4; i++)
        #pragma unroll
        for (int j = 0; j < 4; j++) acc[i][j] = 0;

    #pragma unroll 1
    for (int k0 = 0; k0 < 32; k0++) {
        if (isA) As[lpad] = Ap[k0];
        else if (isB) Bs[lpad] = Wp[k0];
        __syncthreads();
        uint4 a[4], w[4];
        #pragma unroll
        for (int i = 0; i < 4; i++) {
            a[i] = As[pad4(tr * 4 + i)];
            w[i] = Bs[pad4(tn * 4 + i)];
        }
        #pragma unroll
        for (int i = 0; i < 4; i++)
            #pragma unroll
            for (int j = 0; j < 4; j++)
                acc[i][j] = dot16q(w[j], a[i], acc[i][j]);
        __syncthreads();
    }

    #pragma unroll
    for (int i = 0; i < 4; i++) {
        ushort4 o;
        #pragma unroll
        for (int j = 0; j < 4; j++) {
            float r = fmaf((float)acc[i][j], G.sw[n0 + tn * 4 + j], G.bias[n0 + tn * 4 + j]);
            ((ushort*)&o)[j] = f16b(r);
        }
        *(ushort4*)(G.out + (long)(m0 + tr * 4 + i) * G4 + n0 + tn * 4) = o;
    }
}

// int8 GEMM, K=128 (layer 0, A = emb8 gathered, dual scale sA[token] * sW[n])
__device__ void gemm8e_dev(unsigned char* sm, const GJob& G, int bx, int by) {
    uint4* As = (uint4*)sm;          // [144]
    uint4* Bs = As + 144;
    const int tid = threadIdx.x;
    const int m0 = bx * 128, n0 = by * 128;
    const int lr = tid & 127;
    const int lpad = lr + (lr >> 3);
    const bool isA = tid < 128, isB = (tid >= 128 && tid < 256);
    const int tcc = (m0 + lr) & (TC - 1);
    const int bb  = (m0 + lr) >> TCLOG;
    const int tglob = G.tb + G.ts * tcc;
    const long arow = (long)bb * SS + tglob;
    const uint4* Ap = isA ? (const uint4*)(G.A + (long)G.tok[arow] * 128) : nullptr;
    const uint4* Wp = isB ? (const uint4*)(G.W + (long)(n0 + lr) * 128) : nullptr;
    const int tr = tid >> 5, tn = tid & 31;

    int acc[4][4];
    #pragma unroll
    for (int i = 0; i < 4; i++)
        #pragma unroll
        for (int j = 0; j < 4; j++) acc[i][j] = 0;

    #pragma unroll 1
    for (int k0 = 0; k0 < 8; k0++) {
        if (isA) As[lpad] = Ap[k0];
        else if (isB) Bs[lpad] = Wp[k0];
        __syncthreads();
        uint4 a[4], w[4];
        #pragma unroll
        for (int i = 0; i < 4; i++) {
            a[i] = As[pad4(tr * 4 + i)];
            w[i] = Bs[pad4(tn * 4 + i)];
        }
        #pragma unroll
        for (int i = 0; i < 4; i++)
            #pragma unroll
            for (int j = 0; j < 4; j++)
                acc[i][j] = dot16q(w[j], a[i], acc[i][j]);
        __syncthreads();
    }

    // epilogue: per-m token scale, per-n weight scale
    float sA[4];
    #pragma unroll
    for (int i = 0; i < 4; i++) {
        const int m = m0 + tr * 4 + i;
        const int tcc_i = m & (TC - 1);
        const int bb_i  = m >> TCLOG;
        const long ar = (long)bb_i * SS + G.tb + G.ts * tcc_i;
        sA[i] = G.swA[G.tok[ar]];
    }
    float sW[4], bs[4];
    #pragma unroll
    for (int j = 0; j < 4; j++) {
        sW[j] = G.sw[n0 + tn * 4 + j];
        bs[j] = G.bias[n0 + tn * 4 + j];
    }
    #pragma unroll
    for (int i = 0; i < 4; i++) {
        ushort4 o;
        #pragma unroll
        for (int j = 0; j < 4; j++) {
            float r = fmaf((float)acc[i][j] * sA[i], sW[j], bs[j]);
            ((ushort*)&o)[j] = f16b(r);
        }
        *(ushort4*)(G.out + (long)(m0 + tr * 4 + i) * G4 + n0 + tn * 4) = o;
    }
}

// int8-dot LSTM scan (proven body; xg is f16)
__device__ void scan_dev(unsigned char* sm, const SJob& S, int b, int d) {
    const int j = threadIdx.x;
    const ushort* xg = (d ? S.xgB : S.xgF) + (long)b * TC * G4 + j;
    const uint4* wTd = (const uint4*)S.wTq + (long)d * 16 * 1024;

    uint4* lwq = (uint4*)sm;                      // 147456 B
    float* gl  = (float*)(sm + 147456);           // 4096 B
    uint*  hq  = (uint*)(sm + 147456 + 4096);     // 512 B

    #pragma unroll
    for (int kc = 0; kc < KLQ; kc++)
        lwq[kc * 1024 + j] = wTd[(long)kc * 1024 + j];

    const float bj  = S.bhh2[d * G4 + j];
    const float scl = S.swf[d * G4 + j];
    float c_reg = 0.f, h_reg = 0.f;
    if (j < HH) {
        if (!S.doInit) {
            h_reg = S.state[((d * BB + b) * 2 + 0) * HH + j];
            c_reg = S.state[((d * BB + b) * 2 + 1) * HH + j];
        }
        ((char*)hq)[j] = (char)__float2int_rn(h_reg * 127.f);
    }
    __syncthreads();

    #pragma unroll 1
    for (int tc = 0; tc < TC; ++tc) {
        const int rb = tc & 1;
        const uint4* hc = (const uint4*)(hq + rb * 64);
        int isum = 0;
        #pragma unroll
        for (int kc = 0; kc < KLQ; kc++)
            isum = dot16q(lwq[kc * 1024 + j], hc[kc], isum);
        #pragma unroll
        for (int kc = KLQ; kc < 16; kc++)
            isum = dot16q(wTd[(long)kc * 1024 + j], hc[kc], isum);

        float xv = (float)__builtin_bit_cast(_Float16, xg[(long)tc * G4]);
        gl[j] = fmaf((float)isum, scl, xv + bj);
        __syncthreads();
        if (j < HH) {
            float gi = gl[j], gf = gl[j + 256], gg = gl[j + 512], go = gl[j + 768];
            c_reg = sigf(gf) * c_reg + sigf(gi) * tanhfast(gg);
            float h = sigf(go) * tanhfast(c_reg);
            h_reg = h;
            int qh = __float2int_rn(h * 127.f);
            ((char*)(hq + (rb ^ 1) * 64))[j] = (char)qh;
            const int t = d ? (S.tbB - tc) : (S.tbF + tc);
            if (S.doW8) S.hout8[((long)(b * SS + t)) * 512 + d * HH + j] = (unsigned char)(char)qh;
            else        S.hout [((long)(b * SS + t)) * 512 + d * HH + j] = f16b(h);
        }
        __syncthreads();
    }

    if (j < HH) {
        S.state[((d * BB + b) * 2 + 0) * HH + j] = h_reg;
        S.state[((d * BB + b) * 2 + 1) * HH + j] = c_reg;
    }
}

// ---------- mega kernel ----------
__global__ __launch_bounds__(1024, 4) void mega(MegaP p) {
    __shared__ __align__(16) unsigned char sm[152064];
    const int blk = blockIdx.x;
    if (blk < p.nScan * 128) {
        const int local = blk & 127;
        scan_dev(sm, p.s, local & 63, local >> 6);
    } else {
        const int gb = blk - p.nScan * 128;
        const int job = gb >> 9, t = gb & 511;
        const GJob& G = p.g[job];
        if (G.is8 == 1) gemm8_dev(sm, G, t & 63, t >> 6);
        else            gemm8e_dev(sm, G, t & 63, t >> 6);
    }
}

// ---------- preprocessing ----------
__global__ void quant_whh(const float* __restrict__ whh, uint* __restrict__ wTq,
                          float* __restrict__ swf) {
    const int row = blockIdx.x;
    const int t = threadIdx.x;
    float4 v = *(const float4*)(whh + (long)row * 256 + t * 4);
    float mx = fmaxf(fmaxf(fabsf(v.x), fabsf(v.y)), fmaxf(fabsf(v.z), fabsf(v.w)));
    #pragma unroll
    for (int o = 32; o > 0; o >>= 1) mx = fmaxf(mx, __shfl_xor(mx, o));
    float inv = (mx > 0.f) ? 127.f / mx : 0.f;
    int q0 = (int)rintf(v.x * inv) & 255;
    int q1 = (int)rintf(v.y * inv) & 255;
    int q2 = (int)rintf(v.z * inv) & 255;
    int q3 = (int)rintf(v.w * inv) & 255;
    uint u = (uint)q0 | ((uint)q1 << 8) | ((uint)q2 << 16) | ((uint)q3 << 24);
    const int dir = row >> 10, j = row & 1023;
    const int kc = t >> 2, l4 = t & 3;
    wTq[(((long)(dir * 16 + kc) * 1024 + j) << 2) + l4] = u;
    if (t == 0) swf[row] = (mx > 0.f) ? (mx / 127.f) * (1.f / 127.f) : 0.f;
}

// per-row int8 quantize, K = NP*64. mode 0: scale = mx/127 ; mode 1: mx/(127*127)
template <int NP>
__global__ void quant_rows(const float* __restrict__ in, unsigned char* __restrict__ out,
                           float* __restrict__ sc, int mode) {
    const int row = blockIdx.x;
    const int t = threadIdx.x;
    const int K = NP * 64;
    const float* src = in + (long)row * K + t * NP;
    float v[NP];
    float mx = 0.f;
    #pragma unroll
    for (int i = 0; i < NP; i++) { v[i] = src[i]; mx = fmaxf(mx, fabsf(v[i])); }
    #pragma unroll
    for (int o = 32; o > 0; o >>= 1) mx = fmaxf(mx, __shfl_xor(mx, o));
    float inv = (mx > 0.f) ? 127.f / mx : 0.f;
    unsigned char q[NP];
    #pragma unroll
    for (int i = 0; i < NP; i++) q[i] = (unsigned char)((int)rintf(v[i] * inv) & 255);
    unsigned char* dst = out + (long)row * K + t * NP;
    if (NP == 2) {
        *(ushort*)dst = *(ushort*)q;
    } else {
        *(uint*)dst = *(uint*)q;
        *(uint*)(dst + 4) = *(uint*)(q + 4);
    }
    if (t == 0) sc[row] = (mx <= 0.f) ? 0.f
                        : (mode == 0 ? mx / 127.f : mx / (127.f * 127.f));
}

// ---------- tail kernels (proven) ----------
__global__ __launch_bounds__(256) void emissions_k16(
    const ushort* __restrict__ h1, const float* __restrict__ clsw,
    const float* __restrict__ clsb, float* __restrict__ em)
{
    long u = (long)blockIdx.x * 256 + threadIdx.x;
    if (u >= (long)BB * SS * NC) return;
    int c = (int)(u % NC);
    long m = u / NC;
    const uint* hr = (const uint*)(h1 + m * 512);
    const float2* wr = (const float2*)(clsw + (long)c * 512);
    float s0 = 0, s1 = 0;
    #pragma unroll 8
    for (int q = 0; q < 256; q += 2) {
        half2v h0 = __builtin_bit_cast(half2v, hr[q]);
        half2v h1v = __builtin_bit_cast(half2v, hr[q + 1]);
        float2 w0 = wr[q], w1 = wr[q + 1];
        s0 += (float)h0.x * w0.x + (float)h0.y * w0.y;
        s1 += (float)h1v.x * w1.x + (float)h1v.y * w1.y;
    }
    em[u] = s0 + s1 + clsb[c];
}

__global__ __launch_bounds__(64) void crf_llh(
    const float* __restrict__ em, const int* __restrict__ labels,
    const int* __restrict__ mask, const float* __restrict__ start,
    const float* __restrict__ endt, const float* __restrict__ trans,
    float* __restrict__ llh)
{
    int b = blockIdx.x, j = threadIdx.x;
    bool act = j < NC;
    float tcol[NC];
    #pragma unroll
    for (int i = 0; i < NC; i++) tcol[i] = act ? trans[i * NC + j] : 0.f;
    const float* emb_ = em + (long)b * SS * NC;
    const int* lb = labels + b * SS;
    const int* mk = mask + b * SS;
    float alpha = act ? (start[j] + emb_[j]) : -1e30f;

    float num = 0.f;
    int msum = 0;
    for (int t = j; t < SS; t += 64) msum += (mk[t] != 0);
    for (int t = 1 + j; t < SS; t += 64) {
        float m = (float)mk[t];
        num += m * (trans[lb[t - 1] * NC + lb[t]] + emb_[t * NC + lb[t]]);
    }
    for (int o = 32; o > 0; o >>= 1) {
        num  += __shfl_down(num, o);
        msum += __shfl_down(msum, o);
    }
    msum = __shfl(msum, 0);

    for (int t = 1; t < SS; t++) {
        int m = mk[t];
        float emj = act ? emb_[t * NC + j] : 0.f;
        float v[NC];
        float mx = -1e30f;
        #pragma unroll
        for (int i = 0; i < NC; i++) {
            v[i] = __shfl(alpha, i) + tcol[i];
            mx = fmaxf(mx, v[i]);
        }
        float sum = 0.f;
        #pragma unroll
        for (int i = 0; i < NC; i++) sum += __expf(v[i] - mx);
        float nxt = mx + __logf(sum) + emj;
        if (m > 0 && act) alpha = nxt;
    }
    float fin = act ? alpha + endt[j] : -1e30f;
    float mx = -1e30f;
    #pragma unroll
    for (int i = 0; i < NC; i++) mx = fmaxf(mx, __shfl(fin, i));
    float s = 0.f;
    #pragma unroll
    for (int i = 0; i < NC; i++) s += __expf(__shfl(fin, i) - mx);
    float den = mx + __logf(s);
    if (j == 0) {
        int last_idx = msum - 1;
        float numer = num + start[lb[0]] + emb_[lb[0]] + endt[lb[last_idx]];
        llh[b] = numer - den;
    }
}

__global__ __launch_bounds__(64) void loss_k(const float* __restrict__ llh, float* __restrict__ out) {
    int j = threadIdx.x;
    float v = llh[j];
    for (int o = 32; o > 0; o >>= 1) v += __shfl_down(v, o);
    if (j == 0) out[0] = -v / 64.0f;
}

__global__ __launch_bounds__(64) void viterbi_k(
    const float* __restrict__ em, const int* __restrict__ mask,
    const float* __restrict__ start, const float* __restrict__ endt,
    const float* __restrict__ trans, float* __restrict__ outp)
{
    int b = blockIdx.x, j = threadIdx.x;
    bool act = j < NC;
    __shared__ unsigned char bp[SS][NC];
    float tcol[NC];
    #pragma unroll
    for (int i = 0; i < NC; i++) tcol[i] = act ? trans[i * NC + j] : 0.f;
    const float* emb_ = em + (long)b * SS * NC;
    const int* mk = mask + b * SS;
    float score = act ? (start[j] + emb_[j]) : -1e30f;

    for (int t = 1; t < SS; t++) {
        float best = 0.f;
        int bi = 0;
        #pragma unroll
        for (int i = 0; i < NC; i++) {
            float vv = __shfl(score, i) + tcol[i];
            if (i == 0 || vv > best) { best = vv; bi = i; }
        }
        int m = mk[t];
        float nxt = best + (act ? emb_[t * NC + j] : 0.f);
        if (act) {
            if (m > 0) { score = nxt; bp[t][j] = (unsigned char)bi; }
            else       { bp[t][j] = (unsigned char)j; }
        }
    }
    float fin = act ? score + endt[j] : -1e30f;
    float bestf = 0.f;
    int last = 0;
    #pragma unroll
    for (int i = 0; i < NC; i++) {
        float vv = __shfl(fin, i);
        if (i == 0 || vv > bestf) { bestf = vv; last = i; }
    }
    __syncthreads();
    if (j == 0) {
        int cur = last;
        outp[1 + (long)b * SS + (SS - 1)] = (float)cur;
        for (int t = SS - 1; t >= 1; t--) {
            cur = bp[t][cur];
            outp[1 + (long)b * SS + (t - 1)] = (float)cur;
        }
    }
}

extern "C" void kernel_launch(void* const* d_in, const int* in_sizes, int n_in,
                              void* d_out, int out_size, void* d_ws, size_t ws_size,
                              hipStream_t stream) {
    const int*   tok    = (const int*)d_in[0];
    const int*   lab    = (const int*)d_in[1];
    const int*   msk    = (const int*)d_in[2];
    const float* emb    = (const float*)d_in[3];
    const float* w_ih0  = (const float*)d_in[4];
    const float* w_hh0  = (const float*)d_in[5];
    const float* b_ih0  = (const float*)d_in[6];
    const float* b_hh0  = (const float*)d_in[7];
    const float* w_ih1  = (const float*)d_in[8];
    const float* w_hh1  = (const float*)d_in[9];
    const float* b_ih1  = (const float*)d_in[10];
    const float* b_hh1  = (const float*)d_in[11];
    const float* clsw   = (const float*)d_in[12];
    const float* clsb   = (const float*)d_in[13];
    const float* startt = (const float*)d_in[14];
    const float* endt   = (const float*)d_in[15];
    const float* transm = (const float*)d_in[16];
    float* out = (float*)d_out;

    // ---- workspace carve (f32 units); ~203 MB ----
    size_t nH8  = (size_t)BB * SS * 512 / 4;        // int8 H0
    size_t nHh  = (size_t)BB * SS * 512 / 2;        // f16 H1
    size_t xgHalf = (size_t)BB * TC * G4;           // ushorts per dir per chunk
    size_t nXGb = xgHalf * 2 / 2;                   // f32 units per ring buffer
    size_t nWQ  = (size_t)2 * 16 * 1024 * 4;        // whh int8 (uints)
    size_t nSW  = (size_t)2 * 1024;
    size_t nWQ1 = (size_t)2048 * 512 / 4;           // w_ih1 int8 bytes -> units
    size_t nWQ0 = (size_t)2048 * 128 / 4;           // w_ih0 int8
    size_t nE8  = (size_t)VV * 128 / 4;             // emb int8
    size_t nEM  = (size_t)BB * SS * NC;
    size_t nST  = (size_t)2 * BB * 2 * HH;

    float* H08f = (float*)d_ws;
    float* H1f  = H08f + nH8;
    float* XG0a = H1f + nHh;
    float* XG0b = XG0a + nXGb;
    float* XG1a = XG0b + nXGb;
    float* XG1b = XG1a + nXGb;
    float* WQ0  = XG1b + nXGb;
    float* WQ1w = WQ0 + nWQ;
    float* SW0  = WQ1w + nWQ;
    float* SW1  = SW0 + nSW;
    float* WQI1 = SW1 + nSW;
    float* SWI1 = WQI1 + nWQ1;
    float* WQI0 = SWI1 + 2048;
    float* SWI0 = WQI0 + nWQ0;
    float* EMB8 = SWI0 + 2048;
    float* SA   = EMB8 + nE8;
    float* EM   = SA + VV;
    float* ST0  = EM + nEM;
    float* ST1  = ST0 + nST;
    float* LLH  = ST1 + nST;

    unsigned char* H08   = (unsigned char*)H08f;
    ushort*        H1h   = (ushort*)H1f;
    unsigned char* WQI1b = (unsigned char*)WQI1;
    unsigned char* WQI0b = (unsigned char*)WQI0;
    unsigned char* EMB8b = (unsigned char*)EMB8;
    ushort* XG0[2] = {(ushort*)XG0a, (ushort*)XG0b};
    ushort* XG1[2] = {(ushort*)XG1a, (ushort*)XG1b};

    quant_whh<<<2048, 64, 0, stream>>>(w_hh0, (uint*)WQ0, SW0);
    quant_whh<<<2048, 64, 0, stream>>>(w_hh1, (uint*)WQ1w, SW1);
    quant_rows<8><<<2048, 64, 0, stream>>>(w_ih1, WQI1b, SWI1, 1);
    quant_rows<2><<<2048, 64, 0, stream>>>(w_ih0, WQI0b, SWI0, 0);
    quant_rows<2><<<VV, 64, 0, stream>>>(emb, EMB8b, SA, 0);

    auto g0 = [&](int c, int dd) {
        GJob g{};
        g.A = EMB8b; g.tok = tok;
        g.W = WQI0b + (size_t)dd * 1024 * 128;
        g.sw = SWI0 + dd * 1024; g.swA = SA; g.bias = b_ih0 + dd * 1024;
        g.out = XG0[c & 1] + (size_t)dd * xgHalf;
        g.tb = dd ? (SS - 1 - c * TC) : (c * TC);
        g.ts = dd ? -1 : 1;
        g.is8 = 2;
        return g;
    };
    auto g8 = [&](int c, int dd) {
        GJob g{};
        g.A = H08; g.tok = nullptr;
        g.W = WQI1b + (size_t)dd * 1024 * 512;
        g.sw = SWI1 + dd * 1024; g.swA = nullptr; g.bias = b_ih1 + dd * 1024;
        g.out = XG1[c & 1] + (size_t)dd * xgHalf;
        g.tb = dd ? (SS - 1 - c * TC) : (c * TC);
        g.ts = dd ? -1 : 1;
        g.is8 = 1;
        return g;
    };
    auto sj = [&](int layer, int c) {
        SJob s{};
        ushort* xgb = layer ? XG1[c & 1] : XG0[c & 1];
        s.xgF = xgb; s.xgB = xgb + xgHalf;
        s.wTq = (const uint*)(layer ? WQ1w : WQ0);
        s.swf = layer ? SW1 : SW0;
        s.bhh2 = layer ? b_hh1 : b_hh0;
        s.hout = H1h; s.hout8 = H08;
        s.doW8 = layer ? 0 : 1;
        s.state = layer ? ST1 : ST0;
        s.tbF = c * TC; s.tbB = SS - 1 - c * TC;
        s.doInit = (c == 0);
        return s;
    };
    auto launch = [&](int nS, SJob s, GJob* gj, int nG) {
        MegaP p{};
        p.s = s;
        for (int i = 0; i < nG; i++) p.g[i] = gj[i];
        p.nScan = nS; p.nGemm = nG;
        mega<<<nS * 128 + nG * 512, 1024, 0, stream>>>(p);
    };

    // ---- pipeline: 9 megas (round-23 schedule; L0 gemms now int8) ----
    { GJob j2[2] = {g0(0, 0), g0(0, 1)};          launch(0, SJob{}, j2, 2); }   // D1
    { GJob j2[2] = {g0(1, 0), g0(1, 1)};          launch(1, sj(0, 0), j2, 2); } // D2
    { GJob j2[2] = {g0(2, 0), g0(2, 1)};          launch(1, sj(0, 1), j2, 2); } // D3
    { GJob j4[4] = {g0(3, 0), g0(3, 1), g8(0, 0), g8(0, 1)};
                                                   launch(1, sj(0, 2), j4, 4); } // D4
    { GJob j2[2] = {g8(1, 0), g8(1, 1)};          launch(1, sj(0, 3), j2, 2); } // D5
    {                                              launch(1, sj(1, 0), nullptr, 0); } // D6
    { GJob j2[2] = {g8(2, 0), g8(2, 1)};          launch(1, sj(1, 1), j2, 2); } // D7
    { GJob j2[2] = {g8(3, 0), g8(3, 1)};          launch(1, sj(1, 2), j2, 2); } // D8
    {                                              launch(1, sj(1, 3), nullptr, 0); } // D9

    emissions_k16<<<((BB * SS * NC) + 255) / 256, 256, 0, stream>>>(H1h, clsw, clsb, EM);
    crf_llh<<<BB, 64, 0, stream>>>(EM, lab, msk, startt, endt, transm, LLH);
    loss_k<<<1, 64, 0, stream>>>(LLH, out);
    viterbi_k<<<BB, 64, 0, stream>>>(EM, msk, startt, endt, transm, out);
}

// Round 25
// 1914.417 us; speedup vs baseline: 1.2706x; 1.0667x over previous
//
#include <hip/hip_runtime.h>
#include <math.h>

#define BB 64      // batch
#define SS 512     // seq len
#define HH 256     // hidden
#define NC 9       // classes
#define G4 1024    // 4*H gates (one direction)
#define VV 30000   // vocab

#define KLQ 9      // int8 k16 chunks cached in LDS = 144 KB; 7 streamed int8

typedef _Float16 half2v __attribute__((ext_vector_type(2)));

// ---------- activations ----------
__device__ __forceinline__ float sigf(float x) {
    return 1.0f / (1.0f + __expf(-x));
}
__device__ __forceinline__ float tanhfast(float x) {
    float a = fabsf(x);
    float e = __expf(-2.0f * a);
    float t = (1.0f - e) / (1.0f + e);
    return copysignf(t, x);
}
__device__ __forceinline__ int dot16q(uint4 w, uint4 h, int acc) {
    acc = __builtin_amdgcn_sdot4((int)w.x, (int)h.x, acc, false);
    acc = __builtin_amdgcn_sdot4((int)w.y, (int)h.y, acc, false);
    acc = __builtin_amdgcn_sdot4((int)w.z, (int)h.z, acc, false);
    acc = __builtin_amdgcn_sdot4((int)w.w, (int)h.w, acc, false);
    return acc;
}
__device__ __forceinline__ ushort f16b(float x) {
    return __builtin_bit_cast(ushort, (_Float16)x);
}
__device__ __forceinline__ int pad4(int r) { return r + (r >> 3); }

// ---------- preprocessing (proven round-24) ----------
__global__ void quant_whh(const float* __restrict__ whh, uint* __restrict__ wTq,
                          float* __restrict__ swf) {
    const int row = blockIdx.x;
    const int t = threadIdx.x;
    float4 v = *(const float4*)(whh + (long)row * 256 + t * 4);
    float mx = fmaxf(fmaxf(fabsf(v.x), fabsf(v.y)), fmaxf(fabsf(v.z), fabsf(v.w)));
    #pragma unroll
    for (int o = 32; o > 0; o >>= 1) mx = fmaxf(mx, __shfl_xor(mx, o));
    float inv = (mx > 0.f) ? 127.f / mx : 0.f;
    int q0 = (int)rintf(v.x * inv) & 255;
    int q1 = (int)rintf(v.y * inv) & 255;
    int q2 = (int)rintf(v.z * inv) & 255;
    int q3 = (int)rintf(v.w * inv) & 255;
    uint u = (uint)q0 | ((uint)q1 << 8) | ((uint)q2 << 16) | ((uint)q3 << 24);
    const int dir = row >> 10, j = row & 1023;
    const int kc = t >> 2, l4 = t & 3;
    wTq[(((long)(dir * 16 + kc) * 1024 + j) << 2) + l4] = u;
    if (t == 0) swf[row] = (mx > 0.f) ? (mx / 127.f) * (1.f / 127.f) : 0.f;
}

// per-row int8 quantize, K = NP*64. mode 0: scale = mx/127 ; mode 1: mx/(127*127)
template <int NP>
__global__ void quant_rows(const float* __restrict__ in, unsigned char* __restrict__ out,
                           float* __restrict__ sc, int mode) {
    const int row = blockIdx.x;
    const int t = threadIdx.x;
    const int K = NP * 64;
    const float* src = in + (long)row * K + t * NP;
    float v[NP];
    float mx = 0.f;
    #pragma unroll
    for (int i = 0; i < NP; i++) { v[i] = src[i]; mx = fmaxf(mx, fabsf(v[i])); }
    #pragma unroll
    for (int o = 32; o > 0; o >>= 1) mx = fmaxf(mx, __shfl_xor(mx, o));
    float inv = (mx > 0.f) ? 127.f / mx : 0.f;
    unsigned char q[NP];
    #pragma unroll
    for (int i = 0; i < NP; i++) q[i] = (unsigned char)((int)rintf(v[i] * inv) & 255);
    unsigned char* dst = out + (long)row * K + t * NP;
    if (NP == 2) {
        *(ushort*)dst = *(ushort*)q;
    } else {
        *(uint*)dst = *(uint*)q;
        *(uint*)(dst + 4) = *(uint*)(q + 4);
    }
    if (t == 0) sc[row] = (mx <= 0.f) ? 0.f
                        : (mode == 0 ? mx / 127.f : mx / (127.f * 127.f));
}

// ---------- L0 gemm, full S, both dirs: int8 emb x int8 w_ih0 ----------
// grid (256, 8, 2): 128x128 tiles over (B*S) x 1024, z = dir. 1024 threads.
__global__ __launch_bounds__(1024, 2) void gemm8e_k(
    const unsigned char* __restrict__ A8,   // emb8 [V][128]
    const int* __restrict__ tok,            // [B*S]
    const unsigned char* __restrict__ Wq,   // [2][1024][128]
    const float* __restrict__ sw,           // [2][1024]
    const float* __restrict__ swA,          // [V]
    const float* __restrict__ bias,         // [2][1024]
    ushort* __restrict__ xg)                // [2][B*S][1024] f16
{
    __shared__ uint4 As[144], Bs[144];
    const int tid = threadIdx.x;
    const int m0 = blockIdx.x * 128;
    const int n0 = blockIdx.y * 128;
    const int d  = blockIdx.z;
    const unsigned char* W = Wq + (size_t)d * 1024 * 128;
    const float* swd = sw + d * 1024;
    const float* bd  = bias + d * 1024;
    ushort* outd = xg + (size_t)d * BB * SS * G4;

    const int lr = tid & 127;
    const int lpad = lr + (lr >> 3);
    const bool isA = tid < 128, isB = (tid >= 128 && tid < 256);
    const uint4* Ap = isA ? (const uint4*)(A8 + (long)tok[m0 + lr] * 128) : nullptr;
    const uint4* Wp = isB ? (const uint4*)(W + (long)(n0 + lr) * 128) : nullptr;
    const int tr = tid >> 5, tn = tid & 31;

    int acc[4][4];
    #pragma unroll
    for (int i = 0; i < 4; i++)
        #pragma unroll
        for (int j = 0; j < 4; j++) acc[i][j] = 0;

    #pragma unroll 1
    for (int k0 = 0; k0 < 8; k0++) {
        if (isA) As[lpad] = Ap[k0];
        else if (isB) Bs[lpad] = Wp[k0];
        __syncthreads();
        uint4 a[4], w[4];
        #pragma unroll
        for (int i = 0; i < 4; i++) {
            a[i] = As[pad4(tr * 4 + i)];
            w[i] = Bs[pad4(tn * 4 + i)];
        }
        #pragma unroll
        for (int i = 0; i < 4; i++)
            #pragma unroll
            for (int j = 0; j < 4; j++)
                acc[i][j] = dot16q(w[j], a[i], acc[i][j]);
        __syncthreads();
    }

    float sA[4];
    #pragma unroll
    for (int i = 0; i < 4; i++) sA[i] = swA[tok[m0 + tr * 4 + i]];
    float sW[4], bs[4];
    #pragma unroll
    for (int j = 0; j < 4; j++) {
        sW[j] = swd[n0 + tn * 4 + j];
        bs[j] = bd[n0 + tn * 4 + j];
    }
    #pragma unroll
    for (int i = 0; i < 4; i++) {
        ushort4 o;
        #pragma unroll
        for (int j = 0; j < 4; j++) {
            float r = fmaf((float)acc[i][j] * sA[i], sW[j], bs[j]);
            ((ushort*)&o)[j] = f16b(r);
        }
        *(ushort4*)(outd + (long)(m0 + tr * 4 + i) * G4 + n0 + tn * 4) = o;
    }
}

// ---------- L1 gemm, full S, both dirs: int8 H08 x int8 w_ih1 (K=512) ----------
__global__ __launch_bounds__(1024, 2) void gemm8_k(
    const unsigned char* __restrict__ A8,   // H08 [B*S][512] = h*127
    const unsigned char* __restrict__ Wq,   // [2][1024][512]
    const float* __restrict__ sw,           // [2][1024] = maxw/(127*127)
    const float* __restrict__ bias,         // [2][1024]
    ushort* __restrict__ xg)                // [2][B*S][1024] f16
{
    __shared__ uint4 As[144], Bs[144];
    const int tid = threadIdx.x;
    const int m0 = blockIdx.x * 128;
    const int n0 = blockIdx.y * 128;
    const int d  = blockIdx.z;
    const unsigned char* W = Wq + (size_t)d * 1024 * 512;
    const float* swd = sw + d * 1024;
    const float* bd  = bias + d * 1024;
    ushort* outd = xg + (size_t)d * BB * SS * G4;

    const int lr = tid & 127;
    const int lpad = lr + (lr >> 3);
    const bool isA = tid < 128, isB = (tid >= 128 && tid < 256);
    const uint4* Ap = isA ? (const uint4*)(A8 + (long)(m0 + lr) * 512) : nullptr;
    const uint4* Wp = isB ? (const uint4*)(W + (long)(n0 + lr) * 512) : nullptr;
    const int tr = tid >> 5, tn = tid & 31;

    int acc[4][4];
    #pragma unroll
    for (int i = 0; i < 4; i++)
        #pragma unroll
        for (int j = 0; j < 4; j++) acc[i][j] = 0;

    #pragma unroll 1
    for (int k0 = 0; k0 < 32; k0++) {
        if (isA) As[lpad] = Ap[k0];
        else if (isB) Bs[lpad] = Wp[k0];
        __syncthreads();
        uint4 a[4], w[4];
        #pragma unroll
        for (int i = 0; i < 4; i++) {
            a[i] = As[pad4(tr * 4 + i)];
            w[i] = Bs[pad4(tn * 4 + i)];
        }
        #pragma unroll
        for (int i = 0; i < 4; i++)
            #pragma unroll
            for (int j = 0; j < 4; j++)
                acc[i][j] = dot16q(w[j], a[i], acc[i][j]);
        __syncthreads();
    }

    #pragma unroll
    for (int i = 0; i < 4; i++) {
        ushort4 o;
        #pragma unroll
        for (int j = 0; j < 4; j++) {
            float r = fmaf((float)acc[i][j], swd[n0 + tn * 4 + j], bd[n0 + tn * 4 + j]);
            ((ushort*)&o)[j] = f16b(r);
        }
        *(ushort4*)(outd + (long)(m0 + tr * 4 + i) * G4 + n0 + tn * 4) = o;
    }
}

// ---------- int8-dot LSTM scan, full 512 steps (proven body; xg f16 by t) ----------
__global__ __launch_bounds__(1024, 4) void lstm_qscan(
    const ushort* __restrict__ xg,    // [2][B*S][1024] f16, natural t order
    const uint* __restrict__ wTq,     // [2][16][1024][4 uint]
    const float* __restrict__ swf,    // [2][1024]
    const float* __restrict__ bhh2,   // [2][1024]
    ushort* __restrict__ hout,        // f16 H (layer 1)
    unsigned char* __restrict__ hout8,// int8 H (layer 0)
    int doW8)
{
    const int b = blockIdx.x;
    const int d = blockIdx.y;
    const int j = threadIdx.x;
    const ushort* xgd = xg + ((size_t)d * BB * SS + (size_t)b * SS) * G4 + j;
    const uint4* wTd = (const uint4*)wTq + (long)d * 16 * 1024;

    __shared__ __align__(16) uint hq[2][64];   // int8 h packed, 256 B each
    __shared__ float gl[G4];                   // 4 KB gate exchange
    __shared__ uint4 lwq[KLQ * 1024];          // 144 KB int8 weight cache

    #pragma unroll
    for (int kc = 0; kc < KLQ; kc++)
        lwq[kc * 1024 + j] = wTd[(long)kc * 1024 + j];

    const float bj  = bhh2[d * G4 + j];
    const float scl = swf[d * G4 + j];
    float c_reg = 0.f;
    if (j < HH) ((char*)hq[0])[j] = 0;
    __syncthreads();

    #pragma unroll 1
    for (int tc = 0; tc < SS; ++tc) {
        const int rb = tc & 1;
        const int t = d ? (SS - 1 - tc) : tc;
        const uint4* hc = (const uint4*)hq[rb];
        int isum = 0;
        #pragma unroll
        for (int kc = 0; kc < KLQ; kc++)
            isum = dot16q(lwq[kc * 1024 + j], hc[kc], isum);
        #pragma unroll
        for (int kc = KLQ; kc < 16; kc++)
            isum = dot16q(wTd[(long)kc * 1024 + j], hc[kc], isum);

        float xv = (float)__builtin_bit_cast(_Float16, xgd[(long)t * G4]);
        gl[j] = fmaf((float)isum, scl, xv + bj);
        __syncthreads();
        if (j < HH) {
            float gi = gl[j], gf = gl[j + 256], gg = gl[j + 512], go = gl[j + 768];
            c_reg = sigf(gf) * c_reg + sigf(gi) * tanhfast(gg);
            float h = sigf(go) * tanhfast(c_reg);
            int qh = __float2int_rn(h * 127.f);
            ((char*)hq[rb ^ 1])[j] = (char)qh;
            if (doW8) hout8[((long)(b * SS + t)) * 512 + d * HH + j] = (unsigned char)(char)qh;
            else      hout [((long)(b * SS + t)) * 512 + d * HH + j] = f16b(h);
        }
        __syncthreads();
    }
}

// ---------- emissions (f16 h) ----------
__global__ __launch_bounds__(256) void emissions_k16(
    const ushort* __restrict__ h1, const float* __restrict__ clsw,
    const float* __restrict__ clsb, float* __restrict__ em)
{
    long u = (long)blockIdx.x * 256 + threadIdx.x;
    if (u >= (long)BB * SS * NC) return;
    int c = (int)(u % NC);
    long m = u / NC;
    const uint* hr = (const uint*)(h1 + m * 512);
    const float2* wr = (const float2*)(clsw + (long)c * 512);
    float s0 = 0, s1 = 0;
    #pragma unroll 8
    for (int q = 0; q < 256; q += 2) {
        half2v h0 = __builtin_bit_cast(half2v, hr[q]);
        half2v h1v = __builtin_bit_cast(half2v, hr[q + 1]);
        float2 w0 = wr[q], w1 = wr[q + 1];
        s0 += (float)h0.x * w0.x + (float)h0.y * w0.y;
        s1 += (float)h1v.x * w1.x + (float)h1v.y * w1.y;
    }
    em[u] = s0 + s1 + clsb[c];
}

// ---------- fused CRF llh (blocks 0..63) + Viterbi (blocks 64..127) ----------
__global__ __launch_bounds__(64) void crfvit_k(
    const float* __restrict__ em, const int* __restrict__ labels,
    const int* __restrict__ mask, const float* __restrict__ start,
    const float* __restrict__ endt, const float* __restrict__ trans,
    float* __restrict__ llh, float* __restrict__ outp)
{
    __shared__ unsigned char bp[SS][NC];
    const int j = threadIdx.x;
    const bool act = j < NC;
    if (blockIdx.x < BB) {
        // ---- CRF log-likelihood for batch row b ----
        const int b = blockIdx.x;
        float tcol[NC];
        #pragma unroll
        for (int i = 0; i < NC; i++) tcol[i] = act ? trans[i * NC + j] : 0.f;
        const float* emb_ = em + (long)b * SS * NC;
        const int* lb = labels + b * SS;
        const int* mk = mask + b * SS;
        float alpha = act ? (start[j] + emb_[j]) : -1e30f;

        float num = 0.f;
        int msum = 0;
        for (int t = j; t < SS; t += 64) msum += (mk[t] != 0);
        for (int t = 1 + j; t < SS; t += 64) {
            float m = (float)mk[t];
            num += m * (trans[lb[t - 1] * NC + lb[t]] + emb_[t * NC + lb[t]]);
        }
        for (int o = 32; o > 0; o >>= 1) {
            num  += __shfl_down(num, o);
            msum += __shfl_down(msum, o);
        }
        msum = __shfl(msum, 0);

        for (int t = 1; t < SS; t++) {
            int m = mk[t];
            float emj = act ? emb_[t * NC + j] : 0.f;
            float v[NC];
            float mx = -1e30f;
            #pragma unroll
            for (int i = 0; i < NC; i++) {
                v[i] = __shfl(alpha, i) + tcol[i];
                mx = fmaxf(mx, v[i]);
            }
            float sum = 0.f;
            #pragma unroll
            for (int i = 0; i < NC; i++) sum += __expf(v[i] - mx);
            float nxt = mx + __logf(sum) + emj;
            if (m > 0 && act) alpha = nxt;
        }
        float fin = act ? alpha + endt[j] : -1e30f;
        float mx = -1e30f;
        #pragma unroll
        for (int i = 0; i < NC; i++) mx = fmaxf(mx, __shfl(fin, i));
        float s = 0.f;
        #pragma unroll
        for (int i = 0; i < NC; i++) s += __expf(__shfl(fin, i) - mx);
        float den = mx + __logf(s);
        if (j == 0) {
            int last_idx = msum - 1;
            float numer = num + start[lb[0]] + emb_[lb[0]] + endt[lb[last_idx]];
            llh[b] = numer - den;
        }
    } else {
        // ---- Viterbi for batch row b ----
        const int b = blockIdx.x - BB;
        float tcol[NC];
        #pragma unroll
        for (int i = 0; i < NC; i++) tcol[i] = act ? trans[i * NC + j] : 0.f;
        const float* emb_ = em + (long)b * SS * NC;
        const int* mk = mask + b * SS;
        float score = act ? (start[j] + emb_[j]) : -1e30f;

        for (int t = 1; t < SS; t++) {
            float best = 0.f;
            int bi = 0;
            #pragma unroll
            for (int i = 0; i < NC; i++) {
                float vv = __shfl(score, i) + tcol[i];
                if (i == 0 || vv > best) { best = vv; bi = i; }   // first-max (jnp.argmax)
            }
            int m = mk[t];
            float nxt = best + (act ? emb_[t * NC + j] : 0.f);
            if (act) {
                if (m > 0) { score = nxt; bp[t][j] = (unsigned char)bi; }
                else       { bp[t][j] = (unsigned char)j; }
            }
        }
        float fin = act ? score + endt[j] : -1e30f;
        float bestf = 0.f;
        int last = 0;
        #pragma unroll
        for (int i = 0; i < NC; i++) {
            float vv = __shfl(fin, i);
            if (i == 0 || vv > bestf) { bestf = vv; last = i; }
        }
        __syncthreads();
        if (j == 0) {
            int cur = last;
            outp[1 + (long)b * SS + (SS - 1)] = (float)cur;
            for (int t = SS - 1; t >= 1; t--) {
                cur = bp[t][cur];
                outp[1 + (long)b * SS + (t - 1)] = (float)cur;
            }
        }
    }
}

__global__ __launch_bounds__(64) void loss_k(const float* __restrict__ llh, float* __restrict__ out) {
    int j = threadIdx.x;
    float v = llh[j];
    for (int o = 32; o > 0; o >>= 1) v += __shfl_down(v, o);
    if (j == 0) out[0] = -v / 64.0f;
}

extern "C" void kernel_launch(void* const* d_in, const int* in_sizes, int n_in,
                              void* d_out, int out_size, void* d_ws, size_t ws_size,
                              hipStream_t stream) {
    const int*   tok    = (const int*)d_in[0];
    const int*   lab    = (const int*)d_in[1];
    const int*   msk    = (const int*)d_in[2];
    const float* emb    = (const float*)d_in[3];
    const float* w_ih0  = (const float*)d_in[4];
    const float* w_hh0  = (const float*)d_in[5];
    const float* b_ih0  = (const float*)d_in[6];
    const float* b_hh0  = (const float*)d_in[7];
    const float* w_ih1  = (const float*)d_in[8];
    const float* w_hh1  = (const float*)d_in[9];
    const float* b_ih1  = (const float*)d_in[10];
    const float* b_hh1  = (const float*)d_in[11];
    const float* clsw   = (const float*)d_in[12];
    const float* clsb   = (const float*)d_in[13];
    const float* startt = (const float*)d_in[14];
    const float* endt   = (const float*)d_in[15];
    const float* transm = (const float*)d_in[16];
    float* out = (float*)d_out;

    // ---- workspace carve (f32 units); ~192 MB < proven >=215 MB ----
    size_t nH8  = (size_t)BB * SS * 512 / 4;        // int8 H0
    size_t nHh  = (size_t)BB * SS * 512 / 2;        // f16 H1
    size_t nXG  = (size_t)2 * BB * SS * G4 / 2;     // f16 xg, both dirs, full S
    size_t nWQ  = (size_t)2 * 16 * 1024 * 4;        // whh int8 (uints) per layer
    size_t nSW  = (size_t)2 * 1024;
    size_t nWQ1 = (size_t)2048 * 512 / 4;           // w_ih1 int8
    size_t nWQ0 = (size_t)2048 * 128 / 4;           // w_ih0 int8
    size_t nE8  = (size_t)VV * 128 / 4;             // emb int8
    size_t nEM  = (size_t)BB * SS * NC;

    float* H08f = (float*)d_ws;
    float* H1f  = H08f + nH8;
    float* XGf  = H1f + nHh;
    float* WQ0  = XGf + nXG;
    float* WQ1w = WQ0 + nWQ;
    float* SW0  = WQ1w + nWQ;
    float* SW1  = SW0 + nSW;
    float* WQI1 = SW1 + nSW;
    float* SWI1 = WQI1 + nWQ1;
    float* WQI0 = SWI1 + 2048;
    float* SWI0 = WQI0 + nWQ0;
    float* EMB8 = SWI0 + 2048;
    float* SA   = EMB8 + nE8;
    float* EM   = SA + VV;
    float* LLH  = EM + nEM;

    unsigned char* H08   = (unsigned char*)H08f;
    ushort*        H1h   = (ushort*)H1f;
    ushort*        XG    = (ushort*)XGf;
    unsigned char* WQI1b = (unsigned char*)WQI1;
    unsigned char* WQI0b = (unsigned char*)WQI0;
    unsigned char* EMB8b = (unsigned char*)EMB8;

    // ---- preprocessing ----
    quant_whh<<<2048, 64, 0, stream>>>(w_hh0, (uint*)WQ0, SW0);
    quant_whh<<<2048, 64, 0, stream>>>(w_hh1, (uint*)WQ1w, SW1);
    quant_rows<8><<<2048, 64, 0, stream>>>(w_ih1, WQI1b, SWI1, 1);
    quant_rows<2><<<2048, 64, 0, stream>>>(w_ih0, WQI0b, SWI0, 0);
    quant_rows<2><<<VV, 64, 0, stream>>>(emb, EMB8b, SA, 0);

    dim3 gg(BB * SS / 128, G4 / 128, 2);   // (256, 8, 2)
    dim3 rg(BB, 2);                         // 128 blocks, 1024 threads

    // ---- layer 0: full-S gemm, then full-S scan (emits int8 H0) ----
    gemm8e_k<<<gg, 1024, 0, stream>>>(EMB8b, tok, WQI0b, SWI0, SA, b_ih0, XG);
    lstm_qscan<<<rg, 1024, 0, stream>>>(XG, (const uint*)WQ0, SW0, b_hh0, H1h, H08, 1);
    // ---- layer 1: full-S gemm from H08, then full-S scan (emits f16 H1) ----
    gemm8_k<<<gg, 1024, 0, stream>>>(H08, WQI1b, SWI1, b_ih1, XG);
    lstm_qscan<<<rg, 1024, 0, stream>>>(XG, (const uint*)WQ1w, SW1, b_hh1, H1h, H08, 0);

    // ---- tail ----
    emissions_k16<<<((BB * SS * NC) + 255) / 256, 256, 0, stream>>>(H1h, clsw, clsb, EM);
    crfvit_k<<<2 * BB, 64, 0, stream>>>(EM, lab, msk, startt, endt, transm, LLH, out);
    loss_k<<<1, 64, 0, stream>>>(LLH, out);
}